// Round 9
// baseline (54.256 us; speedup 1.0000x reference)
//
#include <hip/hip_runtime.h>
#include <math.h>

#define N_NODES 100000
#define NEDGE 64
#define NFEAT 11
#define EFEAT 30
#define MEM 64
#define TD 16
#define MSGIN 174
#define G3 192
#define NB_BULK 391
#define NSLOT 128
#define NWORK 256
#define FINAL_BID NWORK          // 256
#define GRID_ALL (NWORK + 1)     // 257
#define DONE_MAGIC 0x5A17E000
#define WF_MAGIC   0x7E00F000

// ws layout (bytes)
#define WS_PART_OFF   0
#define WS_STATES_OFF ((size_t)NB_BULK*12*sizeof(double))
#define WS_DONE_OFF   (WS_STATES_OFF + (size_t)NSLOT*MEM*sizeof(float))
#define WS_WFLAG_OFF  (WS_DONE_OFF + 64*sizeof(int))

__device__ __forceinline__ float sigmoidf_(float x) { return 1.f/(1.f+expf(-x)); }

// ================= single kernel: 64 edge + 256 bulk-workers + 1 final =================
__global__ __launch_bounds__(256) void k_all(
    const float* __restrict__ nf, const int* __restrict__ src, const int* __restrict__ dst,
    const float* __restrict__ ts, const float* __restrict__ ef,
    const float* __restrict__ Wnp, const float* __restrict__ bnp,
    const float* __restrict__ Wmsg, const float* __restrict__ bmsg,
    const float* __restrict__ Wih, const float* __restrict__ Whh,
    const float* __restrict__ bih, const float* __restrict__ bhh,
    const float* __restrict__ w0, const float* __restrict__ b0,
    const float* __restrict__ tW, const float* __restrict__ tB,
    const float* __restrict__ Wg, const float* __restrict__ bg,
    const float* __restrict__ Wp, const float* __restrict__ bp,
    double* __restrict__ partials, float* __restrict__ states,
    int* __restrict__ done, int* __restrict__ wflag, float* __restrict__ out)
{
  int t = threadIdx.x;
  int bid = blockIdx.x;
  int lane = t & 63, wv = t >> 6;

  if (bid == FINAL_BID) {
    // ---------------- final block: prestage (overlapped), poll, combine ----------------
    __shared__ __align__(16) float sH[NSLOT][MEM];      // 32 KB
    __shared__ __align__(16) float sWpF[MEM][MEM];      // 16 KB
    __shared__ __align__(16) float sWnpF[NFEAT][MEM];
    __shared__ float sNF[NSLOT][12];
    __shared__ int sEpF[NSLOT], sMapF[NSLOT];
    __shared__ float sWgF[MEM], sBpF[MEM], sBnpF[MEM];
    __shared__ float sE0[4], sE1[4], sS0[4][NFEAT], sQ[4][MEM];
    __shared__ double sA[4][12];
    __shared__ double sTot[12];
    __shared__ double sM[MEM];
    __shared__ double sScal[2];

    if (t < 64) sEpF[t] = src[t];
    else if (t < 128) sEpF[t] = dst[t-64];
    if (t >= 128 && t < 192) { int j=t-128; sWgF[j]=Wg[j]; sBpF[j]=bp[j]; sBnpF[j]=bnp[j]; }
    #pragma unroll
    for (int r = 0; r < 4; r++) ((float4*)&sWpF[0][0])[t + 256*r] = ((const float4*)Wp)[t + 256*r];
    if (t < 176) ((float4*)&sWnpF[0][0])[t] = ((const float4*)Wnp)[t];
    __syncthreads();
    if (t < 128) {
      int id = sEpF[t]; int fo = t;
      for (int i = 0; i < 128; i++) if (sEpF[i] == id) { fo = i; break; }
      sMapF[t] = fo;
    }
    for (int i = t; i < NSLOT*NFEAT; i += 256) {
      int s = i / NFEAT, k = i - s*NFEAT;
      sNF[s][k] = nf[(long)sEpF[s]*NFEAT + k];
    }
    float bg0 = bg[0];

    // poll all 256 worker flags (one lane each, line-disjoint, release/acquire proven protocol)
    {
      int want = WF_MAGIC | t;
      while (__hip_atomic_load(&wflag[t], __ATOMIC_ACQUIRE, __HIP_MEMORY_SCOPE_AGENT) != want)
        __builtin_amdgcn_s_sleep(2);
    }
    __syncthreads();

    // wide-stage states + partials
    #pragma unroll
    for (int r = 0; r < 8; r++) ((float4*)&sH[0][0])[t + 256*r] = ((const float4*)states)[t + 256*r];
    double v[12];
    #pragma unroll
    for (int k=0;k<12;k++) {
      double a = partials[t*12 + k];
      if (t + 256 < NB_BULK) a += partials[(t+256)*12 + k];
      v[k] = a;
    }
    __syncthreads();

    // A: bulk partials butterfly
    #pragma unroll
    for (int off=32; off; off>>=1) {
      #pragma unroll
      for (int k=0;k<12;k++) v[k] += __shfl_down(v[k], off);
    }
    if (lane == 0) { for (int k=0;k<12;k++) sA[wv][k] = v[k]; }

    // B: per-slot e0/e1/q (wave wv handles slots it*4+wv) — R5-proven
    {
      float accE0 = 0.f, accE1 = 0.f, accQ = 0.f, accS0[NFEAT];
      #pragma unroll
      for (int k=0;k<NFEAT;k++) accS0[k] = 0.f;
      for (int it = 0; it < 32; it++) {
        int s = it*4 + wv;
        bool used = (sMapF[s] == s);
        float h0 = sBnpF[lane];
        #pragma unroll
        for (int k=0;k<NFEAT;k++) h0 += sNF[s][k]*sWnpF[k][lane];
        float v0 = h0 * sWgF[lane];
        float v1 = sH[s][lane] * sWgF[lane];
        #pragma unroll
        for (int off=32; off; off>>=1) { v0 += __shfl_xor(v0, off); v1 += __shfl_xor(v1, off); }
        float e0 = used ? expf(v0 + bg0) : 0.f;
        float e1 = used ? expf(v1 + bg0) : 0.f;
        accE0 += e0; accE1 += e1;
        #pragma unroll
        for (int k=0;k<NFEAT;k++) accS0[k] += e0*sNF[s][k];
        accQ += e1 * sH[s][lane];
      }
      if (lane == 0) { sE0[wv] = accE0; sE1[wv] = accE1; for (int k=0;k<NFEAT;k++) sS0[wv][k] = accS0[k]; }
      sQ[wv][lane] = accQ;
    }
    __syncthreads();

    if (t < 12) sTot[t] = sA[0][t] + sA[1][t] + sA[2][t] + sA[3][t];
    if (t == 12) sScal[0] = (double)sE0[0] + (double)sE0[1] + (double)sE0[2] + (double)sE0[3];
    if (t == 13) sScal[1] = (double)sE1[0] + (double)sE1[1] + (double)sE1[2] + (double)sE1[3];
    __syncthreads();

    // C: combine in double — R5-proven
    if (t < MEM) {
      double Eall = sTot[0] - sScal[0];
      double a = Eall * (double)sBnpF[t];
      #pragma unroll
      for (int k=0;k<NFEAT;k++) {
        double S0k = (double)sS0[0][k] + (double)sS0[1][k] + (double)sS0[2][k] + (double)sS0[3][k];
        a += (sTot[1+k] - S0k) * (double)sWnpF[k][t];
      }
      double q = (double)sQ[0][t] + (double)sQ[1][t] + (double)sQ[2][t] + (double)sQ[3][t];
      sM[t] = a + q;
    }
    __syncthreads();
    if (t < MEM) {
      double Eall = sTot[0] - sScal[0];
      double den = Eall + sScal[1];
      double a = 0.0;
      for (int m=0;m<MEM;m++) a += sM[m] * (double)sWpF[m][t];
      out[t] = (float)(a/den + (double)sBpF[t]);
    }
    // reset flags for next replay (magic-keyed: 0 != MAGIC|i, poison != MAGIC|i)
    if (t < 64) done[t] = 0;
    wflag[t] = 0;
    return;
  }

  // ---------------- worker blocks (bid < 256): edges first, then bulk tiles ----------------
  __shared__ float sGb[NFEAT];
  __shared__ float sClb;
  __shared__ float sWb[4][12];

  if (bid < NEDGE) {
    // ---------------- edge block (R2-proven protocol, verbatim) ----------------
    __shared__ int sEp[128], sMap[128], sFirst[128];
    __shared__ float sX[176];
    __shared__ float sMsg[MEM];
    __shared__ float sGi[G3], sGhs[G3], sGhd[G3];
    __shared__ float sNewS[MEM];

    if (t < 64) sEp[t] = src[t];
    else if (t < 128) sEp[t] = dst[t-64];
    __syncthreads();
    if (t < 128) {
      int id = sEp[t]; int fo = t; int fe = t & 63;
      for (int i = 0; i < 128; i++) {
        if (sEp[i] == id) { if (i < fo) fo = i; int ei = i & 63; if (ei < fe) fe = ei; }
      }
      sMap[t] = fo; sFirst[t] = fe;
    }
    __syncthreads();

    int e = bid;
    int ss = sMap[e], dd = sMap[64+e];

    if (t < e) {
      bool c = (sMap[t]==ss) || (sMap[t]==dd) || (sMap[64+t]==ss) || (sMap[64+t]==dd);
      if (c) {
        int want = DONE_MAGIC | t;
        while (__hip_atomic_load(&done[t], __ATOMIC_ACQUIRE, __HIP_MEMORY_SCOPE_AGENT) != want)
          __builtin_amdgcn_s_sleep(2);
      }
    }
    __syncthreads();

    bool initS = (sFirst[ss] == e);
    bool initD = (sFirst[dd] == e);
    if (t < 64) {
      float v;
      if (initS) {
        const float* row = nf + (long)sEp[ss]*NFEAT;
        v = bnp[t];
        #pragma unroll
        for (int k = 0; k < NFEAT; k++) v += row[k]*Wnp[k*MEM + t];
      } else {
        v = __hip_atomic_load(&states[ss*MEM + t], __ATOMIC_RELAXED, __HIP_MEMORY_SCOPE_AGENT);
      }
      sX[t] = v;
    } else if (t < 128) {
      int j = t - 64; float v;
      if (initD) {
        const float* row = nf + (long)sEp[dd]*NFEAT;
        v = bnp[j];
        #pragma unroll
        for (int k = 0; k < NFEAT; k++) v += row[k]*Wnp[k*MEM + j];
      } else {
        v = __hip_atomic_load(&states[dd*MEM + j], __ATOMIC_RELAXED, __HIP_MEMORY_SCOPE_AGENT);
      }
      sX[t] = v;
    } else if (t < 158) {
      sX[t] = ef[e*EFEAT + (t-128)];
    } else if (t < 174) {
      int q = t - 158; float tt = ts[e];
      sX[t] = (q == 0) ? (tt*w0[0] + b0[0]) : sinf(tt*tW[q-1] + tB[q-1]);
    } else if (t < 176) sX[t] = 0.f;
    __syncthreads();

    {
      int mj = t >> 2, mg = t & 3, mk0 = mg*44;
      float w[44];
      #pragma unroll
      for (int kk = 0; kk < 44; kk++) {
        int k = mk0 + kk;
        w[kk] = (k < MSGIN) ? Wmsg[k*MEM + mj] : 0.f;
      }
      float a0=0.f,a1=0.f,a2=0.f,a3=0.f;
      #pragma unroll
      for (int kk=0; kk<44; kk+=4) {
        a0 += w[kk]  * sX[mk0+kk];
        a1 += w[kk+1]* sX[mk0+kk+1];
        a2 += w[kk+2]* sX[mk0+kk+2];
        a3 += w[kk+3]* sX[mk0+kk+3];
      }
      float a = (a0+a1)+(a2+a3);
      a += __shfl_xor(a,1);
      a += __shfl_xor(a,2);
      if (mg == 0) sMsg[mj] = fmaxf(a + bmsg[mj], 0.f);
    }
    __syncthreads();

    if (t < G3) {
      const float4* wi4 = (const float4*)(Wih + t*MEM);
      const float4* wh4 = (const float4*)(Whh + t*MEM);
      float a0=0.f,a1=0.f,a2=0.f,a3=0.f;
      float b0v=0.f,b1v=0.f,b2v=0.f,b3v=0.f;
      float c0=0.f,c1=0.f,c2=0.f,c3=0.f;
      #pragma unroll
      for (int k = 0; k < MEM; k += 4) {
        float4 vi = wi4[k>>2];
        float4 vh = wh4[k>>2];
        a0 += vi.x*sMsg[k];   a1 += vi.y*sMsg[k+1];   a2 += vi.z*sMsg[k+2];   a3 += vi.w*sMsg[k+3];
        b0v+= vh.x*sX[k];     b1v+= vh.y*sX[k+1];     b2v+= vh.z*sX[k+2];     b3v+= vh.w*sX[k+3];
        c0 += vh.x*sX[64+k];  c1 += vh.y*sX[64+k+1];  c2 += vh.z*sX[64+k+2];  c3 += vh.w*sX[64+k+3];
      }
      sGi[t]  = (a0+a1)+(a2+a3) + bih[t];
      sGhs[t] = (b0v+b1v)+(b2v+b3v) + bhh[t];
      sGhd[t] = (c0+c1)+(c2+c3) + bhh[t];
    }
    __syncthreads();

    if (ss != dd) {
      if (t < 128) {
        int j = t & 63;
        bool iss = t < 64;
        float h = sX[t];
        const float* gh = iss ? sGhs : sGhd;
        float r = sigmoidf_(sGi[j] + gh[j]);
        float z = sigmoidf_(sGi[64+j] + gh[64+j]);
        float n = tanhf(sGi[128+j] + r*gh[128+j]);
        float hn = (1.f - z)*n + z*h;
        int slot = iss ? ss : dd;
        __hip_atomic_store(&states[slot*MEM + j], hn, __ATOMIC_RELAXED, __HIP_MEMORY_SCOPE_AGENT);
      }
    } else {
      if (t < 64) {
        float h = sX[t];
        float r = sigmoidf_(sGi[t] + sGhs[t]);
        float z = sigmoidf_(sGi[64+t] + sGhs[64+t]);
        float n = tanhf(sGi[128+t] + r*sGhs[128+t]);
        sNewS[t] = (1.f - z)*n + z*h;
      }
      __syncthreads();
      if (t < G3) {
        const float4* wh4 = (const float4*)(Whh + t*MEM);
        float b0v=0.f,b1v=0.f,b2v=0.f,b3v=0.f;
        #pragma unroll
        for (int k = 0; k < MEM; k += 4) {
          float4 vh = wh4[k>>2];
          b0v += vh.x*sNewS[k];  b1v += vh.y*sNewS[k+1];
          b2v += vh.z*sNewS[k+2]; b3v += vh.w*sNewS[k+3];
        }
        sGhd[t] = (b0v+b1v)+(b2v+b3v) + bhh[t];
      }
      __syncthreads();
      if (t < 64) {
        float h = sNewS[t];
        float r = sigmoidf_(sGi[t] + sGhd[t]);
        float z = sigmoidf_(sGi[64+t] + sGhd[64+t]);
        float n = tanhf(sGi[128+t] + r*sGhd[128+t]);
        float hn = (1.f - z)*n + z*h;
        __hip_atomic_store(&states[ss*MEM + t], hn, __ATOMIC_RELAXED, __HIP_MEMORY_SCOPE_AGENT);
      }
    }
    __threadfence();
    __syncthreads();
    if (t == 0) __hip_atomic_store(&done[e], DONE_MAGIC | e, __ATOMIC_RELEASE, __HIP_MEMORY_SCOPE_AGENT);
  }

  // ---------------- bulk tiles (grid-strided over all 256 worker blocks) ----------------
  __syncthreads();
  if (t < NFEAT) {
    float a = 0.f;
    #pragma unroll
    for (int j=0;j<MEM;j++) a += Wnp[t*MEM+j]*Wg[j];
    sGb[t] = a;
  }
  if (t == NFEAT) {
    float a = bg[0];
    #pragma unroll
    for (int j=0;j<MEM;j++) a += bnp[j]*Wg[j];
    sClb = a;
  }
  __syncthreads();

  for (int tau = bid; tau < NB_BULK; tau += NWORK) {
    float accE = 0.f, accS[NFEAT];
    #pragma unroll
    for (int k=0;k<NFEAT;k++) accS[k]=0.f;
    int row = tau*256 + t;
    if (row < N_NODES) {
      float x[NFEAT];
      #pragma unroll
      for (int k=0;k<NFEAT;k++) x[k] = nf[(long)row*NFEAT + k];
      float l = sClb;
      #pragma unroll
      for (int k=0;k<NFEAT;k++) l += x[k]*sGb[k];
      float e = expf(l);
      accE = e;
      #pragma unroll
      for (int k=0;k<NFEAT;k++) accS[k] = e*x[k];
    }
    #pragma unroll
    for (int off=32; off; off>>=1) {
      accE += __shfl_down(accE, off);
      #pragma unroll
      for (int k=0;k<NFEAT;k++) accS[k] += __shfl_down(accS[k], off);
    }
    if ((t&63)==0) { sWb[wv][0]=accE; for (int k=0;k<NFEAT;k++) sWb[wv][1+k]=accS[k]; }
    __syncthreads();
    if (t < 12) {
      double d = (double)sWb[0][t] + (double)sWb[1][t] + (double)sWb[2][t] + (double)sWb[3][t];
      partials[tau*12 + t] = d;
    }
    __syncthreads();
  }

  __threadfence();
  __syncthreads();
  if (t == 0) __hip_atomic_store(&wflag[bid], WF_MAGIC | bid, __ATOMIC_RELEASE, __HIP_MEMORY_SCOPE_AGENT);
}

extern "C" void kernel_launch(void* const* d_in, const int* in_sizes, int n_in,
                              void* d_out, int out_size, void* d_ws, size_t ws_size,
                              hipStream_t stream) {
  (void)in_sizes; (void)n_in; (void)out_size; (void)ws_size;
  const float* nf   = (const float*)d_in[0];
  const int*   src  = (const int*)d_in[1];
  const int*   dst  = (const int*)d_in[2];
  const float* ts   = (const float*)d_in[3];
  const float* ef   = (const float*)d_in[4];
  const float* Wnp  = (const float*)d_in[5];
  const float* bnp  = (const float*)d_in[6];
  const float* Wmsg = (const float*)d_in[7];
  const float* bmsg = (const float*)d_in[8];
  const float* Wih  = (const float*)d_in[9];
  const float* Whh  = (const float*)d_in[10];
  const float* bih  = (const float*)d_in[11];
  const float* bhh  = (const float*)d_in[12];
  const float* w0   = (const float*)d_in[13];
  const float* b0   = (const float*)d_in[14];
  const float* tW   = (const float*)d_in[15];
  const float* tB   = (const float*)d_in[16];
  const float* Wg   = (const float*)d_in[17];
  const float* bg   = (const float*)d_in[18];
  const float* Wp   = (const float*)d_in[19];
  const float* bp   = (const float*)d_in[20];

  double* partials = (double*)((char*)d_ws + WS_PART_OFF);
  float*  states   = (float*)((char*)d_ws + WS_STATES_OFF);
  int*    done     = (int*)((char*)d_ws + WS_DONE_OFF);
  int*    wflag    = (int*)((char*)d_ws + WS_WFLAG_OFF);
  float*  out      = (float*)d_out;

  k_all<<<GRID_ALL, 256, 0, stream>>>(
      nf, src, dst, ts, ef, Wnp, bnp, Wmsg, bmsg,
      Wih, Whh, bih, bhh, w0, b0, tW, tB, Wg, bg, Wp, bp,
      partials, states, done, wflag, out);
}

// Round 10
// 39.316 us; speedup vs baseline: 1.3800x; 1.3800x over previous
//
#include <hip/hip_runtime.h>
#include <math.h>

#define N_NODES 100000
#define NEDGE 64
#define NFEAT 11
#define EFEAT 30
#define MEM 64
#define TD 16
#define MSGIN 174
#define G3 192
#define NB_BULK 391
#define NSLOT 128
#define DONE_MAGIC 0x5A17E000

// ws layout (bytes)
#define WS_PART_OFF   0
#define WS_STATES_OFF ((size_t)NB_BULK*12*sizeof(double))
#define WS_DONE_OFF   (WS_STATES_OFF + (size_t)NSLOT*MEM*sizeof(float))

__device__ __forceinline__ float sigmoidf_(float x) { return 1.f/(1.f+expf(-x)); }

// ================= k1: 64 edge blocks + 391 bulk blocks =================
__global__ __launch_bounds__(256) void k_main(
    const float* __restrict__ nf, const int* __restrict__ src, const int* __restrict__ dst,
    const float* __restrict__ ts, const float* __restrict__ ef,
    const float* __restrict__ Wnp, const float* __restrict__ bnp,
    const float* __restrict__ Wmsg, const float* __restrict__ bmsg,
    const float* __restrict__ Wih, const float* __restrict__ Whh,
    const float* __restrict__ bih, const float* __restrict__ bhh,
    const float* __restrict__ w0, const float* __restrict__ b0,
    const float* __restrict__ tW, const float* __restrict__ tB,
    const float* __restrict__ Wg, const float* __restrict__ bg,
    double* __restrict__ partials, float* __restrict__ states,
    int* __restrict__ done)
{
  int t = threadIdx.x;
  int bid = blockIdx.x;

  // ---------------- bulk blocks: one 256-row tile, float4-staged ----------------
  if (bid >= NEDGE) {
    __shared__ float sG[NFEAT];
    __shared__ float sCl;
    __shared__ __align__(16) float sTile[256*NFEAT];
    __shared__ float sW[4][12];
    int b = bid - NEDGE;
    int base = b*256;
    int nrows = min(256, N_NODES - base);
    int nf4 = (nrows*NFEAT) >> 2;          // rows are multiples of 4 -> exact
    const float4* src4 = (const float4*)(nf + (size_t)base*NFEAT);
    for (int i = t; i < nf4; i += 256) ((float4*)sTile)[i] = src4[i];
    if (t < NFEAT) {
      float a = 0.f;
      #pragma unroll
      for (int j=0;j<MEM;j++) a += Wnp[t*MEM+j]*Wg[j];
      sG[t] = a;
    }
    if (t == NFEAT) {
      float a = bg[0];
      #pragma unroll
      for (int j=0;j<MEM;j++) a += bnp[j]*Wg[j];
      sCl = a;
    }
    __syncthreads();
    float accE = 0.f, accS[NFEAT];
    #pragma unroll
    for (int k=0;k<NFEAT;k++) accS[k]=0.f;
    if (t < nrows) {
      float x[NFEAT];
      #pragma unroll
      for (int k=0;k<NFEAT;k++) x[k] = sTile[t*NFEAT + k];
      float l = sCl;
      #pragma unroll
      for (int k=0;k<NFEAT;k++) l += x[k]*sG[k];
      float e = expf(l);
      accE = e;
      #pragma unroll
      for (int k=0;k<NFEAT;k++) accS[k] = e*x[k];
    }
    #pragma unroll
    for (int off=32; off; off>>=1) {
      accE += __shfl_down(accE, off);
      #pragma unroll
      for (int k=0;k<NFEAT;k++) accS[k] += __shfl_down(accS[k], off);
    }
    int wv = t>>6;
    if ((t&63)==0) { sW[wv][0]=accE; for (int k=0;k<NFEAT;k++) sW[wv][1+k]=accS[k]; }
    __syncthreads();
    if (t < 12) {
      double d = (double)sW[0][t] + (double)sW[1][t] + (double)sW[2][t] + (double)sW[3][t];
      partials[b*12 + t] = d;   // published to k_fin at kernel boundary
    }
    return;
  }

  // ---------------- edge block (R2-proven protocol; Wmsg loads hoisted) ----------------
  __shared__ int sEp[128], sMap[128], sFirst[128];
  __shared__ float sX[176];
  __shared__ float sMsg[MEM];
  __shared__ float sGi[G3], sGhs[G3], sGhd[G3];
  __shared__ float sNewS[MEM];

  // hoisted: issue the 44 Wmsg loads immediately (input-only; overlaps map+spin)
  int mj = t >> 2, mg = t & 3, mk0 = mg*44;
  float wreg[44];
  #pragma unroll
  for (int kk = 0; kk < 44; kk++) {
    int k = mk0 + kk;
    wreg[kk] = (k < MSGIN) ? Wmsg[k*MEM + mj] : 0.f;
  }

  if (t < 64) sEp[t] = src[t];
  else if (t < 128) sEp[t] = dst[t-64];
  __syncthreads();
  if (t < 128) {
    int id = sEp[t]; int fo = t; int fe = t & 63;
    for (int i = 0; i < 128; i++) {
      if (sEp[i] == id) { if (i < fo) fo = i; int ei = i & 63; if (ei < fe) fe = ei; }
    }
    sMap[t] = fo; sFirst[t] = fe;
  }
  __syncthreads();

  int e = bid;
  int ss = sMap[e], dd = sMap[64+e];

  if (t < e) {
    bool c = (sMap[t]==ss) || (sMap[t]==dd) || (sMap[64+t]==ss) || (sMap[64+t]==dd);
    if (c) {
      int want = DONE_MAGIC | t;
      while (__hip_atomic_load(&done[t], __ATOMIC_ACQUIRE, __HIP_MEMORY_SCOPE_AGENT) != want)
        __builtin_amdgcn_s_sleep(2);
    }
  }
  __syncthreads();

  bool initS = (sFirst[ss] == e);
  bool initD = (sFirst[dd] == e);
  if (t < 64) {
    float v;
    if (initS) {
      const float* row = nf + (long)sEp[ss]*NFEAT;
      v = bnp[t];
      #pragma unroll
      for (int k = 0; k < NFEAT; k++) v += row[k]*Wnp[k*MEM + t];
    } else {
      v = __hip_atomic_load(&states[ss*MEM + t], __ATOMIC_RELAXED, __HIP_MEMORY_SCOPE_AGENT);
    }
    sX[t] = v;
  } else if (t < 128) {
    int j = t - 64; float v;
    if (initD) {
      const float* row = nf + (long)sEp[dd]*NFEAT;
      v = bnp[j];
      #pragma unroll
      for (int k = 0; k < NFEAT; k++) v += row[k]*Wnp[k*MEM + j];
    } else {
      v = __hip_atomic_load(&states[dd*MEM + j], __ATOMIC_RELAXED, __HIP_MEMORY_SCOPE_AGENT);
    }
    sX[t] = v;
  } else if (t < 158) {
    sX[t] = ef[e*EFEAT + (t-128)];
  } else if (t < 174) {
    int q = t - 158; float tt = ts[e];
    sX[t] = (q == 0) ? (tt*w0[0] + b0[0]) : sinf(tt*tW[q-1] + tB[q-1]);
  } else if (t < 176) sX[t] = 0.f;
  __syncthreads();

  {
    float a0=0.f,a1=0.f,a2=0.f,a3=0.f;
    #pragma unroll
    for (int kk=0; kk<44; kk+=4) {
      a0 += wreg[kk]  * sX[mk0+kk];
      a1 += wreg[kk+1]* sX[mk0+kk+1];
      a2 += wreg[kk+2]* sX[mk0+kk+2];
      a3 += wreg[kk+3]* sX[mk0+kk+3];
    }
    float a = (a0+a1)+(a2+a3);
    a += __shfl_xor(a,1);
    a += __shfl_xor(a,2);
    if (mg == 0) sMsg[mj] = fmaxf(a + bmsg[mj], 0.f);
  }
  __syncthreads();

  if (t < G3) {
    const float4* wi4 = (const float4*)(Wih + t*MEM);
    const float4* wh4 = (const float4*)(Whh + t*MEM);
    float a0=0.f,a1=0.f,a2=0.f,a3=0.f;
    float b0v=0.f,b1v=0.f,b2v=0.f,b3v=0.f;
    float c0=0.f,c1=0.f,c2=0.f,c3=0.f;
    #pragma unroll
    for (int k = 0; k < MEM; k += 4) {
      float4 vi = wi4[k>>2];
      float4 vh = wh4[k>>2];
      a0 += vi.x*sMsg[k];   a1 += vi.y*sMsg[k+1];   a2 += vi.z*sMsg[k+2];   a3 += vi.w*sMsg[k+3];
      b0v+= vh.x*sX[k];     b1v+= vh.y*sX[k+1];     b2v+= vh.z*sX[k+2];     b3v+= vh.w*sX[k+3];
      c0 += vh.x*sX[64+k];  c1 += vh.y*sX[64+k+1];  c2 += vh.z*sX[64+k+2];  c3 += vh.w*sX[64+k+3];
    }
    sGi[t]  = (a0+a1)+(a2+a3) + bih[t];
    sGhs[t] = (b0v+b1v)+(b2v+b3v) + bhh[t];
    sGhd[t] = (c0+c1)+(c2+c3) + bhh[t];
  }
  __syncthreads();

  if (ss != dd) {
    if (t < 128) {
      int j = t & 63;
      bool iss = t < 64;
      float h = sX[t];
      const float* gh = iss ? sGhs : sGhd;
      float r = sigmoidf_(sGi[j] + gh[j]);
      float z = sigmoidf_(sGi[64+j] + gh[64+j]);
      float n = tanhf(sGi[128+j] + r*gh[128+j]);
      float hn = (1.f - z)*n + z*h;
      int slot = iss ? ss : dd;
      __hip_atomic_store(&states[slot*MEM + j], hn, __ATOMIC_RELAXED, __HIP_MEMORY_SCOPE_AGENT);
    }
  } else {
    if (t < 64) {
      float h = sX[t];
      float r = sigmoidf_(sGi[t] + sGhs[t]);
      float z = sigmoidf_(sGi[64+t] + sGhs[64+t]);
      float n = tanhf(sGi[128+t] + r*sGhs[128+t]);
      sNewS[t] = (1.f - z)*n + z*h;
    }
    __syncthreads();
    if (t < G3) {
      const float4* wh4 = (const float4*)(Whh + t*MEM);
      float b0v=0.f,b1v=0.f,b2v=0.f,b3v=0.f;
      #pragma unroll
      for (int k = 0; k < MEM; k += 4) {
        float4 vh = wh4[k>>2];
        b0v += vh.x*sNewS[k];  b1v += vh.y*sNewS[k+1];
        b2v += vh.z*sNewS[k+2]; b3v += vh.w*sNewS[k+3];
      }
      sGhd[t] = (b0v+b1v)+(b2v+b3v) + bhh[t];
    }
    __syncthreads();
    if (t < 64) {
      float h = sNewS[t];
      float r = sigmoidf_(sGi[t] + sGhd[t]);
      float z = sigmoidf_(sGi[64+t] + sGhd[64+t]);
      float n = tanhf(sGi[128+t] + r*sGhd[128+t]);
      float hn = (1.f - z)*n + z*h;
      __hip_atomic_store(&states[ss*MEM + t], hn, __ATOMIC_RELAXED, __HIP_MEMORY_SCOPE_AGENT);
    }
  }
  __threadfence();
  __syncthreads();
  if (t == 0) __hip_atomic_store(&done[e], DONE_MAGIC | e, __ATOMIC_RELEASE, __HIP_MEMORY_SCOPE_AGENT);
}

// ================= k2: wide-staged parallel readout + combine (1 block, 1024 thr) =================
__global__ __launch_bounds__(1024) void k_fin(
    const float* __restrict__ nf, const int* __restrict__ src, const int* __restrict__ dst,
    const float* __restrict__ Wnp, const float* __restrict__ bnp,
    const float* __restrict__ Wg, const float* __restrict__ bg,
    const float* __restrict__ Wp, const float* __restrict__ bp,
    const double* __restrict__ partials, const float* __restrict__ states,
    int* __restrict__ done, float* __restrict__ out)
{
  __shared__ __align__(16) float sH[NSLOT][MEM];      // 32 KB
  __shared__ __align__(16) float sWp[MEM][MEM];       // 16 KB
  __shared__ __align__(16) float sWnp[NFEAT][MEM];
  __shared__ float sNF[NSLOT][12];
  __shared__ int sEp[NSLOT], sMap[NSLOT];
  __shared__ float sWg[MEM], sBp[MEM], sBnp[MEM];
  __shared__ float sE0[16], sE1[16], sS0[16][NFEAT], sQ[16][MEM];
  __shared__ double sA[16][12];
  __shared__ double sTot[12];
  __shared__ double sM[MEM];
  __shared__ double sScal[2];

  int t = threadIdx.x, lane = t & 63, wv = t >> 6;
  float bg0 = bg[0];

  // ---- wide staging: all misses issued in parallel ----
  if (t < 64) sEp[t] = src[t];
  else if (t < 128) sEp[t] = dst[t-64];
  if (t >= 128 && t < 192) { int j=t-128; sWg[j]=Wg[j]; sBp[j]=bp[j]; sBnp[j]=bnp[j]; }
  ((float4*)&sH[0][0])[t]        = ((const float4*)states)[t];
  ((float4*)&sH[0][0])[t+1024]   = ((const float4*)states)[t+1024];
  ((float4*)&sWp[0][0])[t]       = ((const float4*)Wp)[t];
  if (t < 176) ((float4*)&sWnp[0][0])[t] = ((const float4*)Wnp)[t];
  double v[12];
  #pragma unroll
  for (int k=0;k<12;k++) v[k] = (t < NB_BULK) ? partials[t*12+k] : 0.0;
  __syncthreads();
  if (t < 128) {
    int id = sEp[t]; int fo = t;
    for (int i = 0; i < 128; i++) if (sEp[i] == id) { fo = i; break; }
    sMap[t] = fo;
  }
  for (int i = t; i < NSLOT*NFEAT; i += 1024) {
    int s = i / NFEAT, k = i - s*NFEAT;
    sNF[s][k] = nf[(long)sEp[s]*NFEAT + k];
  }
  // ---- A: bulk partials butterfly (391 rows over 16 waves) ----
  #pragma unroll
  for (int off=32; off; off>>=1) {
    #pragma unroll
    for (int k=0;k<12;k++) v[k] += __shfl_down(v[k], off);
  }
  if (lane == 0) { for (int k=0;k<12;k++) sA[wv][k] = v[k]; }
  __syncthreads();

  // ---- B: per-slot e0/e1/q — wave wv handles slots it*16+wv (8 iters) ----
  {
    float accE0 = 0.f, accE1 = 0.f, accQ = 0.f, accS0[NFEAT];
    #pragma unroll
    for (int k=0;k<NFEAT;k++) accS0[k] = 0.f;
    for (int it = 0; it < 8; it++) {
      int s = it*16 + wv;
      bool used = (sMap[s] == s);
      float h0 = sBnp[lane];
      #pragma unroll
      for (int k=0;k<NFEAT;k++) h0 += sNF[s][k]*sWnp[k][lane];
      float v0 = h0 * sWg[lane];
      float v1 = sH[s][lane] * sWg[lane];
      #pragma unroll
      for (int off=32; off; off>>=1) { v0 += __shfl_xor(v0, off); v1 += __shfl_xor(v1, off); }
      float e0 = used ? expf(v0 + bg0) : 0.f;
      float e1 = used ? expf(v1 + bg0) : 0.f;
      accE0 += e0; accE1 += e1;
      #pragma unroll
      for (int k=0;k<NFEAT;k++) accS0[k] += e0*sNF[s][k];
      accQ += e1 * sH[s][lane];
    }
    if (lane == 0) { sE0[wv] = accE0; sE1[wv] = accE1; for (int k=0;k<NFEAT;k++) sS0[wv][k] = accS0[k]; }
    sQ[wv][lane] = accQ;
  }
  __syncthreads();

  if (t < 12) {
    double d = 0.0;
    #pragma unroll
    for (int w=0;w<16;w++) d += sA[w][t];
    sTot[t] = d;
  }
  if (t == 12) { double d=0.0; for (int w=0;w<16;w++) d += (double)sE0[w]; sScal[0] = d; }
  if (t == 13) { double d=0.0; for (int w=0;w<16;w++) d += (double)sE1[w]; sScal[1] = d; }
  __syncthreads();

  // ---- C: combine in double ----
  if (t < MEM) {
    double Eall = sTot[0] - sScal[0];
    double a = Eall * (double)sBnp[t];
    #pragma unroll
    for (int k=0;k<NFEAT;k++) {
      double S0k = 0.0;
      #pragma unroll
      for (int w=0;w<16;w++) S0k += (double)sS0[w][k];
      a += (sTot[1+k] - S0k) * (double)sWnp[k][t];
    }
    double q = 0.0;
    #pragma unroll
    for (int w=0;w<16;w++) q += (double)sQ[w][t];
    sM[t] = a + q;
  }
  __syncthreads();
  if (t < MEM) {
    double Eall = sTot[0] - sScal[0];
    double den = Eall + sScal[1];
    double a = 0.0;
    for (int m=0;m<MEM;m++) a += sM[m] * (double)sWp[m][t];
    out[t] = (float)(a/den + (double)sBp[t]);
  }
  // reset done flags for the next replay (magic-keyed: 0 != MAGIC|e, poison != MAGIC|e)
  if (t < NEDGE) done[t] = 0;
}

extern "C" void kernel_launch(void* const* d_in, const int* in_sizes, int n_in,
                              void* d_out, int out_size, void* d_ws, size_t ws_size,
                              hipStream_t stream) {
  (void)in_sizes; (void)n_in; (void)out_size; (void)ws_size;
  const float* nf   = (const float*)d_in[0];
  const int*   src  = (const int*)d_in[1];
  const int*   dst  = (const int*)d_in[2];
  const float* ts   = (const float*)d_in[3];
  const float* ef   = (const float*)d_in[4];
  const float* Wnp  = (const float*)d_in[5];
  const float* bnp  = (const float*)d_in[6];
  const float* Wmsg = (const float*)d_in[7];
  const float* bmsg = (const float*)d_in[8];
  const float* Wih  = (const float*)d_in[9];
  const float* Whh  = (const float*)d_in[10];
  const float* bih  = (const float*)d_in[11];
  const float* bhh  = (const float*)d_in[12];
  const float* w0   = (const float*)d_in[13];
  const float* b0   = (const float*)d_in[14];
  const float* tW   = (const float*)d_in[15];
  const float* tB   = (const float*)d_in[16];
  const float* Wg   = (const float*)d_in[17];
  const float* bg   = (const float*)d_in[18];
  const float* Wp   = (const float*)d_in[19];
  const float* bp   = (const float*)d_in[20];

  double* partials = (double*)((char*)d_ws + WS_PART_OFF);
  float*  states   = (float*)((char*)d_ws + WS_STATES_OFF);
  int*    done     = (int*)((char*)d_ws + WS_DONE_OFF);
  float*  out      = (float*)d_out;

  k_main<<<NEDGE + NB_BULK, 256, 0, stream>>>(
      nf, src, dst, ts, ef, Wnp, bnp, Wmsg, bmsg,
      Wih, Whh, bih, bhh, w0, b0, tW, tB, Wg, bg,
      partials, states, done);
  k_fin<<<1, 1024, 0, stream>>>(nf, src, dst, Wnp, bnp, Wg, bg, Wp, bp,
                                partials, states, done, out);
}

// Round 11
// 38.596 us; speedup vs baseline: 1.4057x; 1.0186x over previous
//
#include <hip/hip_runtime.h>
#include <math.h>

#define N_NODES 100000
#define NEDGE 64
#define NFEAT 11
#define EFEAT 30
#define MEM 64
#define TD 16
#define MSGIN 174
#define G3 192
#define NB_BULK 391
#define NSLOT 128
#define NWORKER (NEDGE + NB_BULK)     // 455
#define FINAL_BID NWORKER             // 455
#define GRID_ALL (NWORKER + 1)        // 456
#define DONE_MAGIC 0x5A17E000
#define WF_MAGIC   0x7E000000

// ws layout (bytes)
#define WS_PART_OFF   0
#define WS_STATES_OFF ((size_t)NB_BULK*12*sizeof(double))
#define WS_DONE_OFF   (WS_STATES_OFF + (size_t)NSLOT*MEM*sizeof(float))
#define WS_WFLAG_OFF  (WS_DONE_OFF + 64*sizeof(int))

__device__ __forceinline__ float sigmoidf_(float x) { return 1.f/(1.f+expf(-x)); }

__global__ __launch_bounds__(256) void k_all(
    const float* __restrict__ nf, const int* __restrict__ src, const int* __restrict__ dst,
    const float* __restrict__ ts, const float* __restrict__ ef,
    const float* __restrict__ Wnp, const float* __restrict__ bnp,
    const float* __restrict__ Wmsg, const float* __restrict__ bmsg,
    const float* __restrict__ Wih, const float* __restrict__ Whh,
    const float* __restrict__ bih, const float* __restrict__ bhh,
    const float* __restrict__ w0, const float* __restrict__ b0,
    const float* __restrict__ tW, const float* __restrict__ tB,
    const float* __restrict__ Wg, const float* __restrict__ bg,
    const float* __restrict__ Wp, const float* __restrict__ bp,
    double* __restrict__ partials, float* __restrict__ states,
    int* __restrict__ done, int* __restrict__ wflag, float* __restrict__ out)
{
  int t = threadIdx.x;
  int bid = blockIdx.x;
  int lane = t & 63, wv = t >> 6;

  if (bid < NEDGE) {
    // ---------------- edge block (R2-proven protocol; quiet release) ----------------
    __shared__ int sEp[128], sMap[128], sFirst[128];
    __shared__ float sX[176];
    __shared__ float sMsg[MEM];
    __shared__ float sGi[G3], sGhs[G3], sGhd[G3];
    __shared__ float sNewS[MEM];

    // hoisted Wmsg register loads (input-only; overlap map+spin)
    int mj = t >> 2, mg = t & 3, mk0 = mg*44;
    float wreg[44];
    #pragma unroll
    for (int kk = 0; kk < 44; kk++) {
      int k = mk0 + kk;
      wreg[kk] = (k < MSGIN) ? Wmsg[k*MEM + mj] : 0.f;
    }

    if (t < 64) sEp[t] = src[t];
    else if (t < 128) sEp[t] = dst[t-64];
    __syncthreads();
    if (t < 128) {
      int id = sEp[t]; int fo = t; int fe = t & 63;
      for (int i = 0; i < 128; i++) {
        if (sEp[i] == id) { if (i < fo) fo = i; int ei = i & 63; if (ei < fe) fe = ei; }
      }
      sMap[t] = fo; sFirst[t] = fe;
    }
    __syncthreads();

    int e = bid;
    int ss = sMap[e], dd = sMap[64+e];

    if (t < e) {
      bool c = (sMap[t]==ss) || (sMap[t]==dd) || (sMap[64+t]==ss) || (sMap[64+t]==dd);
      if (c) {
        int want = DONE_MAGIC | t;
        while (__hip_atomic_load(&done[t], __ATOMIC_ACQUIRE, __HIP_MEMORY_SCOPE_AGENT) != want)
          __builtin_amdgcn_s_sleep(2);
      }
    }
    __syncthreads();

    bool initS = (sFirst[ss] == e);
    bool initD = (sFirst[dd] == e);
    if (t < 64) {
      float v;
      if (initS) {
        const float* row = nf + (long)sEp[ss]*NFEAT;
        v = bnp[t];
        #pragma unroll
        for (int k = 0; k < NFEAT; k++) v += row[k]*Wnp[k*MEM + t];
      } else {
        v = __hip_atomic_load(&states[ss*MEM + t], __ATOMIC_RELAXED, __HIP_MEMORY_SCOPE_AGENT);
      }
      sX[t] = v;
    } else if (t < 128) {
      int j = t - 64; float v;
      if (initD) {
        const float* row = nf + (long)sEp[dd]*NFEAT;
        v = bnp[j];
        #pragma unroll
        for (int k = 0; k < NFEAT; k++) v += row[k]*Wnp[k*MEM + j];
      } else {
        v = __hip_atomic_load(&states[dd*MEM + j], __ATOMIC_RELAXED, __HIP_MEMORY_SCOPE_AGENT);
      }
      sX[t] = v;
    } else if (t < 158) {
      sX[t] = ef[e*EFEAT + (t-128)];
    } else if (t < 174) {
      int q = t - 158; float tt = ts[e];
      sX[t] = (q == 0) ? (tt*w0[0] + b0[0]) : sinf(tt*tW[q-1] + tB[q-1]);
    } else if (t < 176) sX[t] = 0.f;
    __syncthreads();

    {
      float a0=0.f,a1=0.f,a2=0.f,a3=0.f;
      #pragma unroll
      for (int kk=0; kk<44; kk+=4) {
        a0 += wreg[kk]  * sX[mk0+kk];
        a1 += wreg[kk+1]* sX[mk0+kk+1];
        a2 += wreg[kk+2]* sX[mk0+kk+2];
        a3 += wreg[kk+3]* sX[mk0+kk+3];
      }
      float a = (a0+a1)+(a2+a3);
      a += __shfl_xor(a,1);
      a += __shfl_xor(a,2);
      if (mg == 0) sMsg[mj] = fmaxf(a + bmsg[mj], 0.f);
    }
    __syncthreads();

    if (t < G3) {
      const float4* wi4 = (const float4*)(Wih + t*MEM);
      const float4* wh4 = (const float4*)(Whh + t*MEM);
      float a0=0.f,a1=0.f,a2=0.f,a3=0.f;
      float b0v=0.f,b1v=0.f,b2v=0.f,b3v=0.f;
      float c0=0.f,c1=0.f,c2=0.f,c3=0.f;
      #pragma unroll
      for (int k = 0; k < MEM; k += 4) {
        float4 vi = wi4[k>>2];
        float4 vh = wh4[k>>2];
        a0 += vi.x*sMsg[k];   a1 += vi.y*sMsg[k+1];   a2 += vi.z*sMsg[k+2];   a3 += vi.w*sMsg[k+3];
        b0v+= vh.x*sX[k];     b1v+= vh.y*sX[k+1];     b2v+= vh.z*sX[k+2];     b3v+= vh.w*sX[k+3];
        c0 += vh.x*sX[64+k];  c1 += vh.y*sX[64+k+1];  c2 += vh.z*sX[64+k+2];  c3 += vh.w*sX[64+k+3];
      }
      sGi[t]  = (a0+a1)+(a2+a3) + bih[t];
      sGhs[t] = (b0v+b1v)+(b2v+b3v) + bhh[t];
      sGhd[t] = (c0+c1)+(c2+c3) + bhh[t];
    }
    __syncthreads();

    if (ss != dd) {
      if (t < 128) {
        int j = t & 63;
        bool iss = t < 64;
        float h = sX[t];
        const float* gh = iss ? sGhs : sGhd;
        float r = sigmoidf_(sGi[j] + gh[j]);
        float z = sigmoidf_(sGi[64+j] + gh[64+j]);
        float n = tanhf(sGi[128+j] + r*gh[128+j]);
        float hn = (1.f - z)*n + z*h;
        int slot = iss ? ss : dd;
        __hip_atomic_store(&states[slot*MEM + j], hn, __ATOMIC_RELAXED, __HIP_MEMORY_SCOPE_AGENT);
      }
    } else {
      if (t < 64) {
        float h = sX[t];
        float r = sigmoidf_(sGi[t] + sGhs[t]);
        float z = sigmoidf_(sGi[64+t] + sGhs[64+t]);
        float n = tanhf(sGi[128+t] + r*sGhs[128+t]);
        sNewS[t] = (1.f - z)*n + z*h;
      }
      __syncthreads();
      if (t < G3) {
        const float4* wh4 = (const float4*)(Whh + t*MEM);
        float b0v=0.f,b1v=0.f,b2v=0.f,b3v=0.f;
        #pragma unroll
        for (int k = 0; k < MEM; k += 4) {
          float4 vh = wh4[k>>2];
          b0v += vh.x*sNewS[k];  b1v += vh.y*sNewS[k+1];
          b2v += vh.z*sNewS[k+2]; b3v += vh.w*sNewS[k+3];
        }
        sGhd[t] = (b0v+b1v)+(b2v+b3v) + bhh[t];
      }
      __syncthreads();
      if (t < 64) {
        float h = sNewS[t];
        float r = sigmoidf_(sGi[t] + sGhd[t]);
        float z = sigmoidf_(sGi[64+t] + sGhd[64+t]);
        float n = tanhf(sGi[128+t] + r*sGhd[128+t]);
        float hn = (1.f - z)*n + z*h;
        __hip_atomic_store(&states[ss*MEM + t], hn, __ATOMIC_RELAXED, __HIP_MEMORY_SCOPE_AGENT);
      }
    }
    __syncthreads();
    if (t == 0) {
      __threadfence();   // write back L2 once; fence-release pairing
      __hip_atomic_store(&done[e], DONE_MAGIC | e, __ATOMIC_RELAXED, __HIP_MEMORY_SCOPE_AGENT);
      __hip_atomic_store(&wflag[e], WF_MAGIC | e, __ATOMIC_RELAXED, __HIP_MEMORY_SCOPE_AGENT);
    }
    return;
  }

  if (bid < FINAL_BID) {
    // ---------------- bulk block: one 256-row tile, float4-staged ----------------
    __shared__ float sG[NFEAT];
    __shared__ float sCl;
    __shared__ __align__(16) float sTile[256*NFEAT];
    __shared__ float sW[4][12];
    int b = bid - NEDGE;
    int base = b*256;
    int nrows = min(256, N_NODES - base);
    int nf4 = (nrows*NFEAT) >> 2;
    const float4* src4 = (const float4*)(nf + (size_t)base*NFEAT);
    for (int i = t; i < nf4; i += 256) ((float4*)sTile)[i] = src4[i];
    if (t < NFEAT) {
      float a = 0.f;
      #pragma unroll
      for (int j=0;j<MEM;j++) a += Wnp[t*MEM+j]*Wg[j];
      sG[t] = a;
    }
    if (t == NFEAT) {
      float a = bg[0];
      #pragma unroll
      for (int j=0;j<MEM;j++) a += bnp[j]*Wg[j];
      sCl = a;
    }
    __syncthreads();
    float accE = 0.f, accS[NFEAT];
    #pragma unroll
    for (int k=0;k<NFEAT;k++) accS[k]=0.f;
    if (t < nrows) {
      float x[NFEAT];
      #pragma unroll
      for (int k=0;k<NFEAT;k++) x[k] = sTile[t*NFEAT + k];
      float l = sCl;
      #pragma unroll
      for (int k=0;k<NFEAT;k++) l += x[k]*sG[k];
      float e = expf(l);
      accE = e;
      #pragma unroll
      for (int k=0;k<NFEAT;k++) accS[k] = e*x[k];
    }
    #pragma unroll
    for (int off=32; off; off>>=1) {
      accE += __shfl_down(accE, off);
      #pragma unroll
      for (int k=0;k<NFEAT;k++) accS[k] += __shfl_down(accS[k], off);
    }
    if ((t&63)==0) { sW[wv][0]=accE; for (int k=0;k<NFEAT;k++) sW[wv][1+k]=accS[k]; }
    __syncthreads();
    if (t < 12) {
      double d = (double)sW[0][t] + (double)sW[1][t] + (double)sW[2][t] + (double)sW[3][t];
      partials[b*12 + t] = d;
    }
    __syncthreads();
    if (t == 0) {
      __threadfence();
      __hip_atomic_store(&wflag[bid], WF_MAGIC | bid, __ATOMIC_RELAXED, __HIP_MEMORY_SCOPE_AGENT);
    }
    return;
  }

  // ---------------- final block: prestage (overlapped), quiet poll, combine ----------------
  {
    __shared__ __align__(16) float sH[NSLOT][MEM];      // 32 KB
    __shared__ __align__(16) float sWpF[MEM][MEM];      // 16 KB
    __shared__ __align__(16) float sWnpF[NFEAT][MEM];
    __shared__ float sNF[NSLOT][12];
    __shared__ int sEpF[NSLOT], sMapF[NSLOT];
    __shared__ float sWgF[MEM], sBpF[MEM], sBnpF[MEM];
    __shared__ float sE0[4], sE1[4], sS0[4][NFEAT], sQ[4][MEM];
    __shared__ double sA[4][12];
    __shared__ double sTot[12];
    __shared__ double sM[MEM];
    __shared__ double sScal[2];

    // prestage input-only tiles while workers run
    if (t < 64) sEpF[t] = src[t];
    else if (t < 128) sEpF[t] = dst[t-64];
    if (t >= 128 && t < 192) { int j=t-128; sWgF[j]=Wg[j]; sBpF[j]=bp[j]; sBnpF[j]=bnp[j]; }
    #pragma unroll
    for (int r = 0; r < 4; r++) ((float4*)&sWpF[0][0])[t + 256*r] = ((const float4*)Wp)[t + 256*r];
    if (t < 176) ((float4*)&sWnpF[0][0])[t] = ((const float4*)Wnp)[t];
    float bg0 = bg[0];
    __syncthreads();
    if (t < 128) {
      int id = sEpF[t]; int fo = t;
      for (int i = 0; i < 128; i++) if (sEpF[i] == id) { fo = i; break; }
      sMapF[t] = fo;
    }
    for (int i = t; i < NSLOT*NFEAT; i += 256) {
      int s = i / NFEAT, k = i - s*NFEAT;
      sNF[s][k] = nf[(long)sEpF[s]*NFEAT + k];
    }

    // quiet poll: RELAXED loads only (no per-iteration invalidation), backoff sleeps
    {
      int f1 = t, f2 = t + 256;
      bool need2 = (f2 < NWORKER);
      int want1 = WF_MAGIC | f1, want2 = WF_MAGIC | f2;
      __builtin_amdgcn_s_sleep(64);
      while (true) {
        bool d1 = (__hip_atomic_load(&wflag[f1], __ATOMIC_RELAXED, __HIP_MEMORY_SCOPE_AGENT) == want1);
        bool d2 = !need2 || (__hip_atomic_load(&wflag[f2], __ATOMIC_RELAXED, __HIP_MEMORY_SCOPE_AGENT) == want2);
        if (d1 && d2) break;
        __builtin_amdgcn_s_sleep(16);
      }
    }
    __threadfence();     // single acquire fence: pairs with workers' fence+flag
    __syncthreads();

    // wide-stage states + partials (now published)
    #pragma unroll
    for (int r = 0; r < 8; r++) ((float4*)&sH[0][0])[t + 256*r] = ((const float4*)states)[t + 256*r];
    double v[12];
    #pragma unroll
    for (int k=0;k<12;k++) {
      double a = partials[t*12 + k];
      if (t + 256 < NB_BULK) a += partials[(t+256)*12 + k];
      v[k] = a;
    }
    __syncthreads();

    // A: bulk partials butterfly
    #pragma unroll
    for (int off=32; off; off>>=1) {
      #pragma unroll
      for (int k=0;k<12;k++) v[k] += __shfl_down(v[k], off);
    }
    if (lane == 0) { for (int k=0;k<12;k++) sA[wv][k] = v[k]; }

    // B: per-slot e0/e1/q (wave wv handles slots it*4+wv) — R5-proven
    {
      float accE0 = 0.f, accE1 = 0.f, accQ = 0.f, accS0[NFEAT];
      #pragma unroll
      for (int k=0;k<NFEAT;k++) accS0[k] = 0.f;
      for (int it = 0; it < 32; it++) {
        int s = it*4 + wv;
        bool used = (sMapF[s] == s);
        float h0 = sBnpF[lane];
        #pragma unroll
        for (int k=0;k<NFEAT;k++) h0 += sNF[s][k]*sWnpF[k][lane];
        float v0 = h0 * sWgF[lane];
        float v1 = sH[s][lane] * sWgF[lane];
        #pragma unroll
        for (int off=32; off; off>>=1) { v0 += __shfl_xor(v0, off); v1 += __shfl_xor(v1, off); }
        float e0 = used ? expf(v0 + bg0) : 0.f;
        float e1 = used ? expf(v1 + bg0) : 0.f;
        accE0 += e0; accE1 += e1;
        #pragma unroll
        for (int k=0;k<NFEAT;k++) accS0[k] += e0*sNF[s][k];
        accQ += e1 * sH[s][lane];
      }
      if (lane == 0) { sE0[wv] = accE0; sE1[wv] = accE1; for (int k=0;k<NFEAT;k++) sS0[wv][k] = accS0[k]; }
      sQ[wv][lane] = accQ;
    }
    __syncthreads();

    if (t < 12) sTot[t] = sA[0][t] + sA[1][t] + sA[2][t] + sA[3][t];
    if (t == 12) sScal[0] = (double)sE0[0] + (double)sE0[1] + (double)sE0[2] + (double)sE0[3];
    if (t == 13) sScal[1] = (double)sE1[0] + (double)sE1[1] + (double)sE1[2] + (double)sE1[3];
    __syncthreads();

    // C: combine in double — R5-proven
    if (t < MEM) {
      double Eall = sTot[0] - sScal[0];
      double a = Eall * (double)sBnpF[t];
      #pragma unroll
      for (int k=0;k<NFEAT;k++) {
        double S0k = (double)sS0[0][k] + (double)sS0[1][k] + (double)sS0[2][k] + (double)sS0[3][k];
        a += (sTot[1+k] - S0k) * (double)sWnpF[k][t];
      }
      double q = (double)sQ[0][t] + (double)sQ[1][t] + (double)sQ[2][t] + (double)sQ[3][t];
      sM[t] = a + q;
    }
    __syncthreads();
    if (t < MEM) {
      double Eall = sTot[0] - sScal[0];
      double den = Eall + sScal[1];
      double a = 0.0;
      for (int m=0;m<MEM;m++) a += sM[m] * (double)sWpF[m][t];
      out[t] = (float)(a/den + (double)sBpF[t]);
    }
    // reset flags for next replay (magic-keyed: 0 and poison both != MAGIC|i)
    if (t < 64) done[t] = 0;
    for (int i = t; i < NWORKER; i += 256) wflag[i] = 0;
  }
}

extern "C" void kernel_launch(void* const* d_in, const int* in_sizes, int n_in,
                              void* d_out, int out_size, void* d_ws, size_t ws_size,
                              hipStream_t stream) {
  (void)in_sizes; (void)n_in; (void)out_size; (void)ws_size;
  const float* nf   = (const float*)d_in[0];
  const int*   src  = (const int*)d_in[1];
  const int*   dst  = (const int*)d_in[2];
  const float* ts   = (const float*)d_in[3];
  const float* ef   = (const float*)d_in[4];
  const float* Wnp  = (const float*)d_in[5];
  const float* bnp  = (const float*)d_in[6];
  const float* Wmsg = (const float*)d_in[7];
  const float* bmsg = (const float*)d_in[8];
  const float* Wih  = (const float*)d_in[9];
  const float* Whh  = (const float*)d_in[10];
  const float* bih  = (const float*)d_in[11];
  const float* bhh  = (const float*)d_in[12];
  const float* w0   = (const float*)d_in[13];
  const float* b0   = (const float*)d_in[14];
  const float* tW   = (const float*)d_in[15];
  const float* tB   = (const float*)d_in[16];
  const float* Wg   = (const float*)d_in[17];
  const float* bg   = (const float*)d_in[18];
  const float* Wp   = (const float*)d_in[19];
  const float* bp   = (const float*)d_in[20];

  double* partials = (double*)((char*)d_ws + WS_PART_OFF);
  float*  states   = (float*)((char*)d_ws + WS_STATES_OFF);
  int*    done     = (int*)((char*)d_ws + WS_DONE_OFF);
  int*    wflag    = (int*)((char*)d_ws + WS_WFLAG_OFF);
  float*  out      = (float*)d_out;

  k_all<<<GRID_ALL, 256, 0, stream>>>(
      nf, src, dst, ts, ef, Wnp, bnp, Wmsg, bmsg,
      Wih, Whh, bih, bhh, w0, b0, tW, tB, Wg, bg, Wp, bp,
      partials, states, done, wflag, out);
}

// Round 12
// 37.489 us; speedup vs baseline: 1.4472x; 1.0295x over previous
//
#include <hip/hip_runtime.h>
#include <math.h>

#define N_NODES 100000
#define NEDGE 64
#define NFEAT 11
#define EFEAT 30
#define MEM 64
#define TD 16
#define MSGIN 174
#define G3 192
#define NB_BULK 391
#define NSLOT 128
#define DONE_MAGIC 0x5A17E000

// ws layout (bytes)
#define WS_PART_OFF   0
#define WS_STATES_OFF ((size_t)NB_BULK*12*sizeof(double))
#define WS_DONE_OFF   (WS_STATES_OFF + (size_t)NSLOT*MEM*sizeof(float))

__device__ __forceinline__ float sigmoidf_(float x) { return 1.f/(1.f+expf(-x)); }

// ================= k1: 64 edge blocks + 391 bulk blocks (R10-proven, verbatim) =================
__global__ __launch_bounds__(256) void k_main(
    const float* __restrict__ nf, const int* __restrict__ src, const int* __restrict__ dst,
    const float* __restrict__ ts, const float* __restrict__ ef,
    const float* __restrict__ Wnp, const float* __restrict__ bnp,
    const float* __restrict__ Wmsg, const float* __restrict__ bmsg,
    const float* __restrict__ Wih, const float* __restrict__ Whh,
    const float* __restrict__ bih, const float* __restrict__ bhh,
    const float* __restrict__ w0, const float* __restrict__ b0,
    const float* __restrict__ tW, const float* __restrict__ tB,
    const float* __restrict__ Wg, const float* __restrict__ bg,
    double* __restrict__ partials, float* __restrict__ states,
    int* __restrict__ done)
{
  int t = threadIdx.x;
  int bid = blockIdx.x;

  // ---------------- bulk blocks: one 256-row tile, float4-staged ----------------
  if (bid >= NEDGE) {
    __shared__ float sG[NFEAT];
    __shared__ float sCl;
    __shared__ __align__(16) float sTile[256*NFEAT];
    __shared__ float sW[4][12];
    int b = bid - NEDGE;
    int base = b*256;
    int nrows = min(256, N_NODES - base);
    int nf4 = (nrows*NFEAT) >> 2;
    const float4* src4 = (const float4*)(nf + (size_t)base*NFEAT);
    for (int i = t; i < nf4; i += 256) ((float4*)sTile)[i] = src4[i];
    if (t < NFEAT) {
      float a = 0.f;
      #pragma unroll
      for (int j=0;j<MEM;j++) a += Wnp[t*MEM+j]*Wg[j];
      sG[t] = a;
    }
    if (t == NFEAT) {
      float a = bg[0];
      #pragma unroll
      for (int j=0;j<MEM;j++) a += bnp[j]*Wg[j];
      sCl = a;
    }
    __syncthreads();
    float accE = 0.f, accS[NFEAT];
    #pragma unroll
    for (int k=0;k<NFEAT;k++) accS[k]=0.f;
    if (t < nrows) {
      float x[NFEAT];
      #pragma unroll
      for (int k=0;k<NFEAT;k++) x[k] = sTile[t*NFEAT + k];
      float l = sCl;
      #pragma unroll
      for (int k=0;k<NFEAT;k++) l += x[k]*sG[k];
      float e = expf(l);
      accE = e;
      #pragma unroll
      for (int k=0;k<NFEAT;k++) accS[k] = e*x[k];
    }
    #pragma unroll
    for (int off=32; off; off>>=1) {
      accE += __shfl_down(accE, off);
      #pragma unroll
      for (int k=0;k<NFEAT;k++) accS[k] += __shfl_down(accS[k], off);
    }
    int wv = t>>6;
    if ((t&63)==0) { sW[wv][0]=accE; for (int k=0;k<NFEAT;k++) sW[wv][1+k]=accS[k]; }
    __syncthreads();
    if (t < 12) {
      double d = (double)sW[0][t] + (double)sW[1][t] + (double)sW[2][t] + (double)sW[3][t];
      partials[b*12 + t] = d;
    }
    return;
  }

  // ---------------- edge block (R2-proven protocol; Wmsg loads hoisted) ----------------
  __shared__ int sEp[128], sMap[128], sFirst[128];
  __shared__ float sX[176];
  __shared__ float sMsg[MEM];
  __shared__ float sGi[G3], sGhs[G3], sGhd[G3];
  __shared__ float sNewS[MEM];

  int mj = t >> 2, mg = t & 3, mk0 = mg*44;
  float wreg[44];
  #pragma unroll
  for (int kk = 0; kk < 44; kk++) {
    int k = mk0 + kk;
    wreg[kk] = (k < MSGIN) ? Wmsg[k*MEM + mj] : 0.f;
  }

  if (t < 64) sEp[t] = src[t];
  else if (t < 128) sEp[t] = dst[t-64];
  __syncthreads();
  if (t < 128) {
    int id = sEp[t]; int fo = t; int fe = t & 63;
    for (int i = 0; i < 128; i++) {
      if (sEp[i] == id) { if (i < fo) fo = i; int ei = i & 63; if (ei < fe) fe = ei; }
    }
    sMap[t] = fo; sFirst[t] = fe;
  }
  __syncthreads();

  int e = bid;
  int ss = sMap[e], dd = sMap[64+e];

  if (t < e) {
    bool c = (sMap[t]==ss) || (sMap[t]==dd) || (sMap[64+t]==ss) || (sMap[64+t]==dd);
    if (c) {
      int want = DONE_MAGIC | t;
      while (__hip_atomic_load(&done[t], __ATOMIC_ACQUIRE, __HIP_MEMORY_SCOPE_AGENT) != want)
        __builtin_amdgcn_s_sleep(2);
    }
  }
  __syncthreads();

  bool initS = (sFirst[ss] == e);
  bool initD = (sFirst[dd] == e);
  if (t < 64) {
    float v;
    if (initS) {
      const float* row = nf + (long)sEp[ss]*NFEAT;
      v = bnp[t];
      #pragma unroll
      for (int k = 0; k < NFEAT; k++) v += row[k]*Wnp[k*MEM + t];
    } else {
      v = __hip_atomic_load(&states[ss*MEM + t], __ATOMIC_RELAXED, __HIP_MEMORY_SCOPE_AGENT);
    }
    sX[t] = v;
  } else if (t < 128) {
    int j = t - 64; float v;
    if (initD) {
      const float* row = nf + (long)sEp[dd]*NFEAT;
      v = bnp[j];
      #pragma unroll
      for (int k = 0; k < NFEAT; k++) v += row[k]*Wnp[k*MEM + j];
    } else {
      v = __hip_atomic_load(&states[dd*MEM + j], __ATOMIC_RELAXED, __HIP_MEMORY_SCOPE_AGENT);
    }
    sX[t] = v;
  } else if (t < 158) {
    sX[t] = ef[e*EFEAT + (t-128)];
  } else if (t < 174) {
    int q = t - 158; float tt = ts[e];
    sX[t] = (q == 0) ? (tt*w0[0] + b0[0]) : sinf(tt*tW[q-1] + tB[q-1]);
  } else if (t < 176) sX[t] = 0.f;
  __syncthreads();

  {
    float a0=0.f,a1=0.f,a2=0.f,a3=0.f;
    #pragma unroll
    for (int kk=0; kk<44; kk+=4) {
      a0 += wreg[kk]  * sX[mk0+kk];
      a1 += wreg[kk+1]* sX[mk0+kk+1];
      a2 += wreg[kk+2]* sX[mk0+kk+2];
      a3 += wreg[kk+3]* sX[mk0+kk+3];
    }
    float a = (a0+a1)+(a2+a3);
    a += __shfl_xor(a,1);
    a += __shfl_xor(a,2);
    if (mg == 0) sMsg[mj] = fmaxf(a + bmsg[mj], 0.f);
  }
  __syncthreads();

  if (t < G3) {
    const float4* wi4 = (const float4*)(Wih + t*MEM);
    const float4* wh4 = (const float4*)(Whh + t*MEM);
    float a0=0.f,a1=0.f,a2=0.f,a3=0.f;
    float b0v=0.f,b1v=0.f,b2v=0.f,b3v=0.f;
    float c0=0.f,c1=0.f,c2=0.f,c3=0.f;
    #pragma unroll
    for (int k = 0; k < MEM; k += 4) {
      float4 vi = wi4[k>>2];
      float4 vh = wh4[k>>2];
      a0 += vi.x*sMsg[k];   a1 += vi.y*sMsg[k+1];   a2 += vi.z*sMsg[k+2];   a3 += vi.w*sMsg[k+3];
      b0v+= vh.x*sX[k];     b1v+= vh.y*sX[k+1];     b2v+= vh.z*sX[k+2];     b3v+= vh.w*sX[k+3];
      c0 += vh.x*sX[64+k];  c1 += vh.y*sX[64+k+1];  c2 += vh.z*sX[64+k+2];  c3 += vh.w*sX[64+k+3];
    }
    sGi[t]  = (a0+a1)+(a2+a3) + bih[t];
    sGhs[t] = (b0v+b1v)+(b2v+b3v) + bhh[t];
    sGhd[t] = (c0+c1)+(c2+c3) + bhh[t];
  }
  __syncthreads();

  if (ss != dd) {
    if (t < 128) {
      int j = t & 63;
      bool iss = t < 64;
      float h = sX[t];
      const float* gh = iss ? sGhs : sGhd;
      float r = sigmoidf_(sGi[j] + gh[j]);
      float z = sigmoidf_(sGi[64+j] + gh[64+j]);
      float n = tanhf(sGi[128+j] + r*gh[128+j]);
      float hn = (1.f - z)*n + z*h;
      int slot = iss ? ss : dd;
      __hip_atomic_store(&states[slot*MEM + j], hn, __ATOMIC_RELAXED, __HIP_MEMORY_SCOPE_AGENT);
    }
  } else {
    if (t < 64) {
      float h = sX[t];
      float r = sigmoidf_(sGi[t] + sGhs[t]);
      float z = sigmoidf_(sGi[64+t] + sGhs[64+t]);
      float n = tanhf(sGi[128+t] + r*sGhs[128+t]);
      sNewS[t] = (1.f - z)*n + z*h;
    }
    __syncthreads();
    if (t < G3) {
      const float4* wh4 = (const float4*)(Whh + t*MEM);
      float b0v=0.f,b1v=0.f,b2v=0.f,b3v=0.f;
      #pragma unroll
      for (int k = 0; k < MEM; k += 4) {
        float4 vh = wh4[k>>2];
        b0v += vh.x*sNewS[k];  b1v += vh.y*sNewS[k+1];
        b2v += vh.z*sNewS[k+2]; b3v += vh.w*sNewS[k+3];
      }
      sGhd[t] = (b0v+b1v)+(b2v+b3v) + bhh[t];
    }
    __syncthreads();
    if (t < 64) {
      float h = sNewS[t];
      float r = sigmoidf_(sGi[t] + sGhd[t]);
      float z = sigmoidf_(sGi[64+t] + sGhd[64+t]);
      float n = tanhf(sGi[128+t] + r*sGhd[128+t]);
      float hn = (1.f - z)*n + z*h;
      __hip_atomic_store(&states[ss*MEM + t], hn, __ATOMIC_RELAXED, __HIP_MEMORY_SCOPE_AGENT);
    }
  }
  __threadfence();
  __syncthreads();
  if (t == 0) __hip_atomic_store(&done[e], DONE_MAGIC | e, __ATOMIC_RELEASE, __HIP_MEMORY_SCOPE_AGENT);
}

// ================= k2: SLIM readout + combine (1 block, 1024 thr, ~17 KB LDS) =================
__global__ __launch_bounds__(1024) void k_fin(
    const float* __restrict__ nf, const int* __restrict__ src, const int* __restrict__ dst,
    const float* __restrict__ Wnp, const float* __restrict__ bnp,
    const float* __restrict__ Wg, const float* __restrict__ bg,
    const float* __restrict__ Wp, const float* __restrict__ bp,
    const double* __restrict__ partials, const float* __restrict__ states,
    int* __restrict__ done, float* __restrict__ out)
{
  __shared__ __align__(16) float sWnp[NFEAT][MEM];    // 2.75 KB
  __shared__ float sNF[NSLOT][12];                    // 6 KB
  __shared__ int sEp[NSLOT], sMap[NSLOT];
  __shared__ float sWg[MEM], sBnp[MEM];
  __shared__ float sE0[16], sE1[16], sS0[16][NFEAT], sQ[16][MEM];
  __shared__ double sA[16][12];
  __shared__ double sTot[12];
  __shared__ double sM[MEM];
  __shared__ double sScal[2];

  int t = threadIdx.x, lane = t & 63, wv = t >> 6;
  float bg0 = bg[0];

  // ---- light staging only: endpoints, Wnp, small vectors, partials regs ----
  if (t < 64) sEp[t] = src[t];
  else if (t < 128) sEp[t] = dst[t-64];
  if (t >= 128 && t < 192) { int j=t-128; sWg[j]=Wg[j]; sBnp[j]=bnp[j]; }
  if (t < 176) ((float4*)&sWnp[0][0])[t] = ((const float4*)Wnp)[t];
  double v[12];
  #pragma unroll
  for (int k=0;k<12;k++) v[k] = (t < NB_BULK) ? partials[t*12+k] : 0.0;
  __syncthreads();
  if (t < 128) {
    int id = sEp[t]; int fo = t;
    for (int i = 0; i < 128; i++) if (sEp[i] == id) { fo = i; break; }
    sMap[t] = fo;
  }
  for (int i = t; i < NSLOT*NFEAT; i += 1024) {
    int s = i / NFEAT, k = i - s*NFEAT;
    sNF[s][k] = nf[(long)sEp[s]*NFEAT + k];
  }
  // ---- A: bulk partials butterfly (in parallel with map/NF settling) ----
  #pragma unroll
  for (int off=32; off; off>>=1) {
    #pragma unroll
    for (int k=0;k<12;k++) v[k] += __shfl_down(v[k], off);
  }
  if (lane == 0) { for (int k=0;k<12;k++) sA[wv][k] = v[k]; }
  __syncthreads();

  // ---- B: per-slot e0/e1/q — states read DIRECT from global, 8 unrolled iters ----
  {
    float accE0 = 0.f, accE1 = 0.f, accQ = 0.f, accS0[NFEAT];
    #pragma unroll
    for (int k=0;k<NFEAT;k++) accS0[k] = 0.f;
    #pragma unroll
    for (int it = 0; it < 8; it++) {
      int s = it*16 + wv;
      bool used = (sMap[s] == s);
      float h = states[s*MEM + lane];      // direct LLC read (kernel boundary published)
      float h0 = sBnp[lane];
      #pragma unroll
      for (int k=0;k<NFEAT;k++) h0 += sNF[s][k]*sWnp[k][lane];
      float v0 = h0 * sWg[lane];
      float v1 = h * sWg[lane];
      #pragma unroll
      for (int off=32; off; off>>=1) { v0 += __shfl_xor(v0, off); v1 += __shfl_xor(v1, off); }
      float e0 = used ? expf(v0 + bg0) : 0.f;
      float e1 = used ? expf(v1 + bg0) : 0.f;
      accE0 += e0; accE1 += e1;
      #pragma unroll
      for (int k=0;k<NFEAT;k++) accS0[k] += e0*sNF[s][k];
      accQ += e1 * h;
    }
    if (lane == 0) { sE0[wv] = accE0; sE1[wv] = accE1; for (int k=0;k<NFEAT;k++) sS0[wv][k] = accS0[k]; }
    sQ[wv][lane] = accQ;
  }
  __syncthreads();

  if (t < 12) {
    double d = 0.0;
    #pragma unroll
    for (int w=0;w<16;w++) d += sA[w][t];
    sTot[t] = d;
  }
  if (t == 12) { double d=0.0; for (int w=0;w<16;w++) d += (double)sE0[w]; sScal[0] = d; }
  if (t == 13) { double d=0.0; for (int w=0;w<16;w++) d += (double)sE1[w]; sScal[1] = d; }
  __syncthreads();

  // ---- C: combine in double; Wp read DIRECT from global ----
  if (t < MEM) {
    double Eall = sTot[0] - sScal[0];
    double a = Eall * (double)sBnp[t];
    #pragma unroll
    for (int k=0;k<NFEAT;k++) {
      double S0k = 0.0;
      #pragma unroll
      for (int w=0;w<16;w++) S0k += (double)sS0[w][k];
      a += (sTot[1+k] - S0k) * (double)sWnp[k][t];
    }
    double q = 0.0;
    #pragma unroll
    for (int w=0;w<16;w++) q += (double)sQ[w][t];
    sM[t] = a + q;
  }
  __syncthreads();
  if (t < MEM) {
    double Eall = sTot[0] - sScal[0];
    double den = Eall + sScal[1];
    double a = 0.0;
    #pragma unroll
    for (int m=0;m<MEM;m++) a += sM[m] * (double)Wp[m*MEM + t];   // direct, unrolled
    out[t] = (float)(a/den + (double)bp[t]);
  }
  // reset done flags for the next replay (magic-keyed: 0 != MAGIC|e, poison != MAGIC|e)
  if (t < NEDGE) done[t] = 0;
}

extern "C" void kernel_launch(void* const* d_in, const int* in_sizes, int n_in,
                              void* d_out, int out_size, void* d_ws, size_t ws_size,
                              hipStream_t stream) {
  (void)in_sizes; (void)n_in; (void)out_size; (void)ws_size;
  const float* nf   = (const float*)d_in[0];
  const int*   src  = (const int*)d_in[1];
  const int*   dst  = (const int*)d_in[2];
  const float* ts   = (const float*)d_in[3];
  const float* ef   = (const float*)d_in[4];
  const float* Wnp  = (const float*)d_in[5];
  const float* bnp  = (const float*)d_in[6];
  const float* Wmsg = (const float*)d_in[7];
  const float* bmsg = (const float*)d_in[8];
  const float* Wih  = (const float*)d_in[9];
  const float* Whh  = (const float*)d_in[10];
  const float* bih  = (const float*)d_in[11];
  const float* bhh  = (const float*)d_in[12];
  const float* w0   = (const float*)d_in[13];
  const float* b0   = (const float*)d_in[14];
  const float* tW   = (const float*)d_in[15];
  const float* tB   = (const float*)d_in[16];
  const float* Wg   = (const float*)d_in[17];
  const float* bg   = (const float*)d_in[18];
  const float* Wp   = (const float*)d_in[19];
  const float* bp   = (const float*)d_in[20];

  double* partials = (double*)((char*)d_ws + WS_PART_OFF);
  float*  states   = (float*)((char*)d_ws + WS_STATES_OFF);
  int*    done     = (int*)((char*)d_ws + WS_DONE_OFF);
  float*  out      = (float*)d_out;

  k_main<<<NEDGE + NB_BULK, 256, 0, stream>>>(
      nf, src, dst, ts, ef, Wnp, bnp, Wmsg, bmsg,
      Wih, Whh, bih, bhh, w0, b0, tW, tB, Wg, bg,
      partials, states, done);
  k_fin<<<1, 1024, 0, stream>>>(nf, src, dst, Wnp, bnp, Wg, bg, Wp, bp,
                                partials, states, done, out);
}

// Round 13
// 35.238 us; speedup vs baseline: 1.5397x; 1.0639x over previous
//
#include <hip/hip_runtime.h>
#include <math.h>

#define N_NODES 100000
#define NEDGE 64
#define NFEAT 11
#define EFEAT 30
#define MEM 64
#define TD 16
#define MSGIN 174
#define G3 192
#define NB_BULK 391
#define NSLOT 128
#define DONE_MAGIC 0x5A17E000

// ws layout (bytes)
#define WS_PART_OFF   0
#define WS_STATES_OFF ((size_t)NB_BULK*12*sizeof(double))
#define WS_DONE_OFF   (WS_STATES_OFF + (size_t)NSLOT*MEM*sizeof(float))

__device__ __forceinline__ float sigmoidf_(float x) { return 1.f/(1.f+expf(-x)); }

// ================= k1: 64 edge blocks + 391 bulk blocks =================
__global__ __launch_bounds__(256) void k_main(
    const float* __restrict__ nf, const int* __restrict__ src, const int* __restrict__ dst,
    const float* __restrict__ ts, const float* __restrict__ ef,
    const float* __restrict__ Wnp, const float* __restrict__ bnp,
    const float* __restrict__ Wmsg, const float* __restrict__ bmsg,
    const float* __restrict__ Wih, const float* __restrict__ Whh,
    const float* __restrict__ bih, const float* __restrict__ bhh,
    const float* __restrict__ w0, const float* __restrict__ b0,
    const float* __restrict__ tW, const float* __restrict__ tB,
    const float* __restrict__ Wg, const float* __restrict__ bg,
    double* __restrict__ partials, float* __restrict__ states,
    int* __restrict__ done)
{
  int t = threadIdx.x;
  int bid = blockIdx.x;

  // ---------------- bulk blocks: one 256-row tile, float4-staged ----------------
  if (bid >= NEDGE) {
    __shared__ float sG[NFEAT];
    __shared__ float sCl;
    __shared__ __align__(16) float sTile[256*NFEAT];
    __shared__ float sW[4][12];
    int b = bid - NEDGE;
    int base = b*256;
    int nrows = min(256, N_NODES - base);
    int nf4 = (nrows*NFEAT) >> 2;
    const float4* src4 = (const float4*)(nf + (size_t)base*NFEAT);
    for (int i = t; i < nf4; i += 256) ((float4*)sTile)[i] = src4[i];
    if (t < NFEAT) {
      float a = 0.f;
      #pragma unroll
      for (int j=0;j<MEM;j++) a += Wnp[t*MEM+j]*Wg[j];
      sG[t] = a;
    }
    if (t == NFEAT) {
      float a = bg[0];
      #pragma unroll
      for (int j=0;j<MEM;j++) a += bnp[j]*Wg[j];
      sCl = a;
    }
    __syncthreads();
    float accE = 0.f, accS[NFEAT];
    #pragma unroll
    for (int k=0;k<NFEAT;k++) accS[k]=0.f;
    if (t < nrows) {
      float x[NFEAT];
      #pragma unroll
      for (int k=0;k<NFEAT;k++) x[k] = sTile[t*NFEAT + k];
      float l = sCl;
      #pragma unroll
      for (int k=0;k<NFEAT;k++) l += x[k]*sG[k];
      float e = expf(l);
      accE = e;
      #pragma unroll
      for (int k=0;k<NFEAT;k++) accS[k] = e*x[k];
    }
    #pragma unroll
    for (int off=32; off; off>>=1) {
      accE += __shfl_down(accE, off);
      #pragma unroll
      for (int k=0;k<NFEAT;k++) accS[k] += __shfl_down(accS[k], off);
    }
    int wv = t>>6;
    if ((t&63)==0) { sW[wv][0]=accE; for (int k=0;k<NFEAT;k++) sW[wv][1+k]=accS[k]; }
    __syncthreads();
    if (t < 12) {
      double d = (double)sW[0][t] + (double)sW[1][t] + (double)sW[2][t] + (double)sW[3][t];
      partials[b*12 + t] = d;
    }
    return;
  }

  // ---------------- edge block (R2-proven protocol; fence removed: release-store orders) ----------------
  __shared__ int sEp[128], sMap[128], sFirst[128];
  __shared__ float sX[176];
  __shared__ float sMsg[MEM];
  __shared__ float sGi[G3], sGhs[G3], sGhd[G3];
  __shared__ float sNewS[MEM];

  int mj = t >> 2, mg = t & 3, mk0 = mg*44;
  float wreg[44];
  #pragma unroll
  for (int kk = 0; kk < 44; kk++) {
    int k = mk0 + kk;
    wreg[kk] = (k < MSGIN) ? Wmsg[k*MEM + mj] : 0.f;
  }

  if (t < 64) sEp[t] = src[t];
  else if (t < 128) sEp[t] = dst[t-64];
  __syncthreads();
  if (t < 128) {
    int id = sEp[t]; int fo = t; int fe = t & 63;
    for (int i = 0; i < 128; i++) {
      if (sEp[i] == id) { if (i < fo) fo = i; int ei = i & 63; if (ei < fe) fe = ei; }
    }
    sMap[t] = fo; sFirst[t] = fe;
  }
  __syncthreads();

  int e = bid;
  int ss = sMap[e], dd = sMap[64+e];

  if (t < e) {
    bool c = (sMap[t]==ss) || (sMap[t]==dd) || (sMap[64+t]==ss) || (sMap[64+t]==dd);
    if (c) {
      int want = DONE_MAGIC | t;
      while (__hip_atomic_load(&done[t], __ATOMIC_ACQUIRE, __HIP_MEMORY_SCOPE_AGENT) != want)
        __builtin_amdgcn_s_sleep(2);
    }
  }
  __syncthreads();

  bool initS = (sFirst[ss] == e);
  bool initD = (sFirst[dd] == e);
  if (t < 64) {
    float v;
    if (initS) {
      const float* row = nf + (long)sEp[ss]*NFEAT;
      v = bnp[t];
      #pragma unroll
      for (int k = 0; k < NFEAT; k++) v += row[k]*Wnp[k*MEM + t];
    } else {
      v = __hip_atomic_load(&states[ss*MEM + t], __ATOMIC_RELAXED, __HIP_MEMORY_SCOPE_AGENT);
    }
    sX[t] = v;
  } else if (t < 128) {
    int j = t - 64; float v;
    if (initD) {
      const float* row = nf + (long)sEp[dd]*NFEAT;
      v = bnp[j];
      #pragma unroll
      for (int k = 0; k < NFEAT; k++) v += row[k]*Wnp[k*MEM + j];
    } else {
      v = __hip_atomic_load(&states[dd*MEM + j], __ATOMIC_RELAXED, __HIP_MEMORY_SCOPE_AGENT);
    }
    sX[t] = v;
  } else if (t < 158) {
    sX[t] = ef[e*EFEAT + (t-128)];
  } else if (t < 174) {
    int q = t - 158; float tt = ts[e];
    sX[t] = (q == 0) ? (tt*w0[0] + b0[0]) : sinf(tt*tW[q-1] + tB[q-1]);
  } else if (t < 176) sX[t] = 0.f;
  __syncthreads();

  {
    float a0=0.f,a1=0.f,a2=0.f,a3=0.f;
    #pragma unroll
    for (int kk=0; kk<44; kk+=4) {
      a0 += wreg[kk]  * sX[mk0+kk];
      a1 += wreg[kk+1]* sX[mk0+kk+1];
      a2 += wreg[kk+2]* sX[mk0+kk+2];
      a3 += wreg[kk+3]* sX[mk0+kk+3];
    }
    float a = (a0+a1)+(a2+a3);
    a += __shfl_xor(a,1);
    a += __shfl_xor(a,2);
    if (mg == 0) sMsg[mj] = fmaxf(a + bmsg[mj], 0.f);
  }
  __syncthreads();

  if (t < G3) {
    const float4* wi4 = (const float4*)(Wih + t*MEM);
    const float4* wh4 = (const float4*)(Whh + t*MEM);
    float a0=0.f,a1=0.f,a2=0.f,a3=0.f;
    float b0v=0.f,b1v=0.f,b2v=0.f,b3v=0.f;
    float c0=0.f,c1=0.f,c2=0.f,c3=0.f;
    #pragma unroll
    for (int k = 0; k < MEM; k += 4) {
      float4 vi = wi4[k>>2];
      float4 vh = wh4[k>>2];
      a0 += vi.x*sMsg[k];   a1 += vi.y*sMsg[k+1];   a2 += vi.z*sMsg[k+2];   a3 += vi.w*sMsg[k+3];
      b0v+= vh.x*sX[k];     b1v+= vh.y*sX[k+1];     b2v+= vh.z*sX[k+2];     b3v+= vh.w*sX[k+3];
      c0 += vh.x*sX[64+k];  c1 += vh.y*sX[64+k+1];  c2 += vh.z*sX[64+k+2];  c3 += vh.w*sX[64+k+3];
    }
    sGi[t]  = (a0+a1)+(a2+a3) + bih[t];
    sGhs[t] = (b0v+b1v)+(b2v+b3v) + bhh[t];
    sGhd[t] = (c0+c1)+(c2+c3) + bhh[t];
  }
  __syncthreads();

  if (ss != dd) {
    if (t < 128) {
      int j = t & 63;
      bool iss = t < 64;
      float h = sX[t];
      const float* gh = iss ? sGhs : sGhd;
      float r = sigmoidf_(sGi[j] + gh[j]);
      float z = sigmoidf_(sGi[64+j] + gh[64+j]);
      float n = tanhf(sGi[128+j] + r*gh[128+j]);
      float hn = (1.f - z)*n + z*h;
      int slot = iss ? ss : dd;
      __hip_atomic_store(&states[slot*MEM + j], hn, __ATOMIC_RELAXED, __HIP_MEMORY_SCOPE_AGENT);
    }
  } else {
    if (t < 64) {
      float h = sX[t];
      float r = sigmoidf_(sGi[t] + sGhs[t]);
      float z = sigmoidf_(sGi[64+t] + sGhs[64+t]);
      float n = tanhf(sGi[128+t] + r*sGhs[128+t]);
      sNewS[t] = (1.f - z)*n + z*h;
    }
    __syncthreads();
    if (t < G3) {
      const float4* wh4 = (const float4*)(Whh + t*MEM);
      float b0v=0.f,b1v=0.f,b2v=0.f,b3v=0.f;
      #pragma unroll
      for (int k = 0; k < MEM; k += 4) {
        float4 vh = wh4[k>>2];
        b0v += vh.x*sNewS[k];  b1v += vh.y*sNewS[k+1];
        b2v += vh.z*sNewS[k+2]; b3v += vh.w*sNewS[k+3];
      }
      sGhd[t] = (b0v+b1v)+(b2v+b3v) + bhh[t];
    }
    __syncthreads();
    if (t < 64) {
      float h = sNewS[t];
      float r = sigmoidf_(sGi[t] + sGhd[t]);
      float z = sigmoidf_(sGi[64+t] + sGhd[64+t]);
      float n = tanhf(sGi[128+t] + r*sGhd[128+t]);
      float hn = (1.f - z)*n + z*h;
      __hip_atomic_store(&states[ss*MEM + t], hn, __ATOMIC_RELAXED, __HIP_MEMORY_SCOPE_AGENT);
    }
  }
  // all lanes' sc1 stores drained by the compiler's s_waitcnt vmcnt(0) before s_barrier;
  // the RELEASE flag store then orders them agent-visibly (threadfence removed — redundant)
  __syncthreads();
  if (t == 0) __hip_atomic_store(&done[e], DONE_MAGIC | e, __ATOMIC_RELEASE, __HIP_MEMORY_SCOPE_AGENT);
}

// ================= k2: SLIM readout + combine (1 block, 1024 thr, ~17 KB LDS) =================
__global__ __launch_bounds__(1024) void k_fin(
    const float* __restrict__ nf, const int* __restrict__ src, const int* __restrict__ dst,
    const float* __restrict__ Wnp, const float* __restrict__ bnp,
    const float* __restrict__ Wg, const float* __restrict__ bg,
    const float* __restrict__ Wp, const float* __restrict__ bp,
    const double* __restrict__ partials, const float* __restrict__ states,
    int* __restrict__ done, float* __restrict__ out)
{
  __shared__ __align__(16) float sWnp[NFEAT][MEM];
  __shared__ float sNF[NSLOT][12];
  __shared__ int sEp[NSLOT], sMap[NSLOT];
  __shared__ float sWg[MEM], sBnp[MEM];
  __shared__ float sE0[16], sE1[16], sS0[16][NFEAT], sQ[16][MEM];
  __shared__ double sA[16][12];
  __shared__ double sTot[12];
  __shared__ double sM[MEM];
  __shared__ double sScal[2];

  int t = threadIdx.x, lane = t & 63, wv = t >> 6;
  float bg0 = bg[0];

  if (t < 64) sEp[t] = src[t];
  else if (t < 128) sEp[t] = dst[t-64];
  if (t >= 128 && t < 192) { int j=t-128; sWg[j]=Wg[j]; sBnp[j]=bnp[j]; }
  if (t < 176) ((float4*)&sWnp[0][0])[t] = ((const float4*)Wnp)[t];
  double v[12];
  #pragma unroll
  for (int k=0;k<12;k++) v[k] = (t < NB_BULK) ? partials[t*12+k] : 0.0;
  __syncthreads();
  if (t < 128) {
    int id = sEp[t]; int fo = t;
    for (int i = 0; i < 128; i++) if (sEp[i] == id) { fo = i; break; }
    sMap[t] = fo;
  }
  for (int i = t; i < NSLOT*NFEAT; i += 1024) {
    int s = i / NFEAT, k = i - s*NFEAT;
    sNF[s][k] = nf[(long)sEp[s]*NFEAT + k];
  }
  #pragma unroll
  for (int off=32; off; off>>=1) {
    #pragma unroll
    for (int k=0;k<12;k++) v[k] += __shfl_down(v[k], off);
  }
  if (lane == 0) { for (int k=0;k<12;k++) sA[wv][k] = v[k]; }
  __syncthreads();

  {
    float accE0 = 0.f, accE1 = 0.f, accQ = 0.f, accS0[NFEAT];
    #pragma unroll
    for (int k=0;k<NFEAT;k++) accS0[k] = 0.f;
    #pragma unroll
    for (int it = 0; it < 8; it++) {
      int s = it*16 + wv;
      bool used = (sMap[s] == s);
      float h = states[s*MEM + lane];
      float h0 = sBnp[lane];
      #pragma unroll
      for (int k=0;k<NFEAT;k++) h0 += sNF[s][k]*sWnp[k][lane];
      float v0 = h0 * sWg[lane];
      float v1 = h * sWg[lane];
      #pragma unroll
      for (int off=32; off; off>>=1) { v0 += __shfl_xor(v0, off); v1 += __shfl_xor(v1, off); }
      float e0 = used ? expf(v0 + bg0) : 0.f;
      float e1 = used ? expf(v1 + bg0) : 0.f;
      accE0 += e0; accE1 += e1;
      #pragma unroll
      for (int k=0;k<NFEAT;k++) accS0[k] += e0*sNF[s][k];
      accQ += e1 * h;
    }
    if (lane == 0) { sE0[wv] = accE0; sE1[wv] = accE1; for (int k=0;k<NFEAT;k++) sS0[wv][k] = accS0[k]; }
    sQ[wv][lane] = accQ;
  }
  __syncthreads();

  if (t < 12) {
    double d = 0.0;
    #pragma unroll
    for (int w=0;w<16;w++) d += sA[w][t];
    sTot[t] = d;
  }
  if (t == 12) { double d=0.0; for (int w=0;w<16;w++) d += (double)sE0[w]; sScal[0] = d; }
  if (t == 13) { double d=0.0; for (int w=0;w<16;w++) d += (double)sE1[w]; sScal[1] = d; }
  __syncthreads();

  if (t < MEM) {
    double Eall = sTot[0] - sScal[0];
    double a = Eall * (double)sBnp[t];
    #pragma unroll
    for (int k=0;k<NFEAT;k++) {
      double S0k = 0.0;
      #pragma unroll
      for (int w=0;w<16;w++) S0k += (double)sS0[w][k];
      a += (sTot[1+k] - S0k) * (double)sWnp[k][t];
    }
    double q = 0.0;
    #pragma unroll
    for (int w=0;w<16;w++) q += (double)sQ[w][t];
    sM[t] = a + q;
  }
  __syncthreads();
  if (t < MEM) {
    double Eall = sTot[0] - sScal[0];
    double den = Eall + sScal[1];
    double a = 0.0;
    #pragma unroll
    for (int m=0;m<MEM;m++) a += sM[m] * (double)Wp[m*MEM + t];
    out[t] = (float)(a/den + (double)bp[t]);
  }
  if (t < NEDGE) done[t] = 0;
}

extern "C" void kernel_launch(void* const* d_in, const int* in_sizes, int n_in,
                              void* d_out, int out_size, void* d_ws, size_t ws_size,
                              hipStream_t stream) {
  (void)in_sizes; (void)n_in; (void)out_size; (void)ws_size;
  const float* nf   = (const float*)d_in[0];
  const int*   src  = (const int*)d_in[1];
  const int*   dst  = (const int*)d_in[2];
  const float* ts   = (const float*)d_in[3];
  const float* ef   = (const float*)d_in[4];
  const float* Wnp  = (const float*)d_in[5];
  const float* bnp  = (const float*)d_in[6];
  const float* Wmsg = (const float*)d_in[7];
  const float* bmsg = (const float*)d_in[8];
  const float* Wih  = (const float*)d_in[9];
  const float* Whh  = (const float*)d_in[10];
  const float* bih  = (const float*)d_in[11];
  const float* bhh  = (const float*)d_in[12];
  const float* w0   = (const float*)d_in[13];
  const float* b0   = (const float*)d_in[14];
  const float* tW   = (const float*)d_in[15];
  const float* tB   = (const float*)d_in[16];
  const float* Wg   = (const float*)d_in[17];
  const float* bg   = (const float*)d_in[18];
  const float* Wp   = (const float*)d_in[19];
  const float* bp   = (const float*)d_in[20];

  double* partials = (double*)((char*)d_ws + WS_PART_OFF);
  float*  states   = (float*)((char*)d_ws + WS_STATES_OFF);
  int*    done     = (int*)((char*)d_ws + WS_DONE_OFF);
  float*  out      = (float*)d_out;

  k_main<<<NEDGE + NB_BULK, 256, 0, stream>>>(
      nf, src, dst, ts, ef, Wnp, bnp, Wmsg, bmsg,
      Wih, Whh, bih, bhh, w0, b0, tW, tB, Wg, bg,
      partials, states, done);
  k_fin<<<1, 1024, 0, stream>>>(nf, src, dst, Wnp, bnp, Wg, bg, Wp, bp,
                                partials, states, done, out);
}

// Round 14
// 34.622 us; speedup vs baseline: 1.5671x; 1.0178x over previous
//
#include <hip/hip_runtime.h>
#include <math.h>

#define N_NODES 100000
#define NEDGE 64
#define NFEAT 11
#define EFEAT 30
#define MEM 64
#define TD 16
#define MSGIN 174
#define G3 192
#define ROWS_PB 1024
#define NB_BULK 98            // ceil(100000/1024)
#define NSLOT 128
#define DONE_MAGIC 0x5A17E000

// ws layout (bytes)
#define WS_PART_OFF   0
#define WS_STATES_OFF ((size_t)NB_BULK*12*sizeof(double))
#define WS_DONE_OFF   (WS_STATES_OFF + (size_t)NSLOT*MEM*sizeof(float))

__device__ __forceinline__ float sigmoidf_(float x) { return 1.f/(1.f+expf(-x)); }

// ================= k1: 64 edge blocks + 98 bulk blocks =================
__global__ __launch_bounds__(256) void k_main(
    const float* __restrict__ nf, const int* __restrict__ src, const int* __restrict__ dst,
    const float* __restrict__ ts, const float* __restrict__ ef,
    const float* __restrict__ Wnp, const float* __restrict__ bnp,
    const float* __restrict__ Wmsg, const float* __restrict__ bmsg,
    const float* __restrict__ Wih, const float* __restrict__ Whh,
    const float* __restrict__ bih, const float* __restrict__ bhh,
    const float* __restrict__ w0, const float* __restrict__ b0,
    const float* __restrict__ tW, const float* __restrict__ tB,
    const float* __restrict__ Wg, const float* __restrict__ bg,
    double* __restrict__ partials, float* __restrict__ states,
    int* __restrict__ done)
{
  int t = threadIdx.x;
  int bid = blockIdx.x;

  // ---------------- bulk blocks: 1024-row tile (4 x 256 rows), float4-staged ----------------
  if (bid >= NEDGE) {
    __shared__ float sG[NFEAT];
    __shared__ float sCl;
    __shared__ __align__(16) float sTile[ROWS_PB*NFEAT];   // 44 KB
    __shared__ float sW[4][12];
    int b = bid - NEDGE;
    long base = (long)b*ROWS_PB;
    int nrows = (int)min((long)ROWS_PB, (long)N_NODES - base);
    int nf4 = (nrows*NFEAT) >> 2;                          // rows multiple of 4 -> exact
    const float4* src4 = (const float4*)(nf + base*NFEAT);
    for (int i = t; i < nf4; i += 256) ((float4*)sTile)[i] = src4[i];
    if (t < NFEAT) {
      float a = 0.f;
      #pragma unroll
      for (int j=0;j<MEM;j++) a += Wnp[t*MEM+j]*Wg[j];
      sG[t] = a;
    }
    if (t == NFEAT) {
      float a = bg[0];
      #pragma unroll
      for (int j=0;j<MEM;j++) a += bnp[j]*Wg[j];
      sCl = a;
    }
    __syncthreads();
    float accE = 0.f, accS[NFEAT];
    #pragma unroll
    for (int k=0;k<NFEAT;k++) accS[k]=0.f;
    #pragma unroll
    for (int rr = 0; rr < 4; rr++) {
      int row = rr*256 + t;
      if (row < nrows) {
        float x[NFEAT];
        #pragma unroll
        for (int k=0;k<NFEAT;k++) x[k] = sTile[row*NFEAT + k];
        float l = sCl;
        #pragma unroll
        for (int k=0;k<NFEAT;k++) l += x[k]*sG[k];
        float e = expf(l);
        accE += e;
        #pragma unroll
        for (int k=0;k<NFEAT;k++) accS[k] += e*x[k];
      }
    }
    #pragma unroll
    for (int off=32; off; off>>=1) {
      accE += __shfl_down(accE, off);
      #pragma unroll
      for (int k=0;k<NFEAT;k++) accS[k] += __shfl_down(accS[k], off);
    }
    int wv = t>>6;
    if ((t&63)==0) { sW[wv][0]=accE; for (int k=0;k<NFEAT;k++) sW[wv][1+k]=accS[k]; }
    __syncthreads();
    if (t < 12) {
      double d = (double)sW[0][t] + (double)sW[1][t] + (double)sW[2][t] + (double)sW[3][t];
      partials[b*12 + t] = d;
    }
    return;
  }

  // ---------------- edge block (proven protocol; plain state stores, release-ordered) ----------------
  __shared__ int sEp[128], sMap[128], sFirst[128];
  __shared__ float sX[176];
  __shared__ float sMsg[MEM];
  __shared__ float sGi[G3], sGhs[G3], sGhd[G3];
  __shared__ float sNewS[MEM];

  int mj = t >> 2, mg = t & 3, mk0 = mg*44;
  float wreg[44];
  #pragma unroll
  for (int kk = 0; kk < 44; kk++) {
    int k = mk0 + kk;
    wreg[kk] = (k < MSGIN) ? Wmsg[k*MEM + mj] : 0.f;
  }

  if (t < 64) sEp[t] = src[t];
  else if (t < 128) sEp[t] = dst[t-64];
  __syncthreads();
  if (t < 128) {
    int id = sEp[t]; int fo = t; int fe = t & 63;
    for (int i = 0; i < 128; i++) {
      if (sEp[i] == id) { if (i < fo) fo = i; int ei = i & 63; if (ei < fe) fe = ei; }
    }
    sMap[t] = fo; sFirst[t] = fe;
  }
  __syncthreads();

  int e = bid;
  int ss = sMap[e], dd = sMap[64+e];

  if (t < e) {
    bool c = (sMap[t]==ss) || (sMap[t]==dd) || (sMap[64+t]==ss) || (sMap[64+t]==dd);
    if (c) {
      int want = DONE_MAGIC | t;
      while (__hip_atomic_load(&done[t], __ATOMIC_ACQUIRE, __HIP_MEMORY_SCOPE_AGENT) != want)
        __builtin_amdgcn_s_sleep(2);
    }
  }
  __syncthreads();

  bool initS = (sFirst[ss] == e);
  bool initD = (sFirst[dd] == e);
  if (t < 64) {
    float v;
    if (initS) {
      const float* row = nf + (long)sEp[ss]*NFEAT;
      v = bnp[t];
      #pragma unroll
      for (int k = 0; k < NFEAT; k++) v += row[k]*Wnp[k*MEM + t];
    } else {
      v = states[ss*MEM + t];      // plain load: ordered by acquire spin above
    }
    sX[t] = v;
  } else if (t < 128) {
    int j = t - 64; float v;
    if (initD) {
      const float* row = nf + (long)sEp[dd]*NFEAT;
      v = bnp[j];
      #pragma unroll
      for (int k = 0; k < NFEAT; k++) v += row[k]*Wnp[k*MEM + j];
    } else {
      v = states[dd*MEM + j];      // plain load
    }
    sX[t] = v;
  } else if (t < 158) {
    sX[t] = ef[e*EFEAT + (t-128)];
  } else if (t < 174) {
    int q = t - 158; float tt = ts[e];
    sX[t] = (q == 0) ? (tt*w0[0] + b0[0]) : sinf(tt*tW[q-1] + tB[q-1]);
  } else if (t < 176) sX[t] = 0.f;
  __syncthreads();

  {
    float a0=0.f,a1=0.f,a2=0.f,a3=0.f;
    #pragma unroll
    for (int kk=0; kk<44; kk+=4) {
      a0 += wreg[kk]  * sX[mk0+kk];
      a1 += wreg[kk+1]* sX[mk0+kk+1];
      a2 += wreg[kk+2]* sX[mk0+kk+2];
      a3 += wreg[kk+3]* sX[mk0+kk+3];
    }
    float a = (a0+a1)+(a2+a3);
    a += __shfl_xor(a,1);
    a += __shfl_xor(a,2);
    if (mg == 0) sMsg[mj] = fmaxf(a + bmsg[mj], 0.f);
  }
  __syncthreads();

  if (t < G3) {
    const float4* wi4 = (const float4*)(Wih + t*MEM);
    const float4* wh4 = (const float4*)(Whh + t*MEM);
    float a0=0.f,a1=0.f,a2=0.f,a3=0.f;
    float b0v=0.f,b1v=0.f,b2v=0.f,b3v=0.f;
    float c0=0.f,c1=0.f,c2=0.f,c3=0.f;
    #pragma unroll
    for (int k = 0; k < MEM; k += 4) {
      float4 vi = wi4[k>>2];
      float4 vh = wh4[k>>2];
      a0 += vi.x*sMsg[k];   a1 += vi.y*sMsg[k+1];   a2 += vi.z*sMsg[k+2];   a3 += vi.w*sMsg[k+3];
      b0v+= vh.x*sX[k];     b1v+= vh.y*sX[k+1];     b2v+= vh.z*sX[k+2];     b3v+= vh.w*sX[k+3];
      c0 += vh.x*sX[64+k];  c1 += vh.y*sX[64+k+1];  c2 += vh.z*sX[64+k+2];  c3 += vh.w*sX[64+k+3];
    }
    sGi[t]  = (a0+a1)+(a2+a3) + bih[t];
    sGhs[t] = (b0v+b1v)+(b2v+b3v) + bhh[t];
    sGhd[t] = (c0+c1)+(c2+c3) + bhh[t];
  }
  __syncthreads();

  if (ss != dd) {
    if (t < 128) {
      int j = t & 63;
      bool iss = t < 64;
      float h = sX[t];
      const float* gh = iss ? sGhs : sGhd;
      float r = sigmoidf_(sGi[j] + gh[j]);
      float z = sigmoidf_(sGi[64+j] + gh[64+j]);
      float n = tanhf(sGi[128+j] + r*gh[128+j]);
      float hn = (1.f - z)*n + z*h;
      int slot = iss ? ss : dd;
      states[slot*MEM + j] = hn;   // plain store: ordered by RELEASE flag below
    }
  } else {
    if (t < 64) {
      float h = sX[t];
      float r = sigmoidf_(sGi[t] + sGhs[t]);
      float z = sigmoidf_(sGi[64+t] + sGhs[64+t]);
      float n = tanhf(sGi[128+t] + r*sGhs[128+t]);
      sNewS[t] = (1.f - z)*n + z*h;
    }
    __syncthreads();
    if (t < G3) {
      const float4* wh4 = (const float4*)(Whh + t*MEM);
      float b0v=0.f,b1v=0.f,b2v=0.f,b3v=0.f;
      #pragma unroll
      for (int k = 0; k < MEM; k += 4) {
        float4 vh = wh4[k>>2];
        b0v += vh.x*sNewS[k];  b1v += vh.y*sNewS[k+1];
        b2v += vh.z*sNewS[k+2]; b3v += vh.w*sNewS[k+3];
      }
      sGhd[t] = (b0v+b1v)+(b2v+b3v) + bhh[t];
    }
    __syncthreads();
    if (t < 64) {
      float h = sNewS[t];
      float r = sigmoidf_(sGi[t] + sGhd[t]);
      float z = sigmoidf_(sGi[64+t] + sGhd[64+t]);
      float n = tanhf(sGi[128+t] + r*sGhd[128+t]);
      float hn = (1.f - z)*n + z*h;
      states[ss*MEM + t] = hn;     // plain store
    }
  }
  __syncthreads();
  if (t == 0) __hip_atomic_store(&done[e], DONE_MAGIC | e, __ATOMIC_RELEASE, __HIP_MEMORY_SCOPE_AGENT);
}

// ================= k2: SLIM readout + combine (1 block, 1024 thr) =================
__global__ __launch_bounds__(1024) void k_fin(
    const float* __restrict__ nf, const int* __restrict__ src, const int* __restrict__ dst,
    const float* __restrict__ Wnp, const float* __restrict__ bnp,
    const float* __restrict__ Wg, const float* __restrict__ bg,
    const float* __restrict__ Wp, const float* __restrict__ bp,
    const double* __restrict__ partials, const float* __restrict__ states,
    int* __restrict__ done, float* __restrict__ out)
{
  __shared__ __align__(16) float sWnp[NFEAT][MEM];
  __shared__ float sNF[NSLOT][12];
  __shared__ int sEp[NSLOT], sMap[NSLOT];
  __shared__ float sWg[MEM], sBnp[MEM];
  __shared__ float sE0[16], sE1[16], sS0[16][NFEAT], sQ[16][MEM];
  __shared__ double sA[16][12];
  __shared__ double sTot[12];
  __shared__ double sM[MEM];
  __shared__ double sScal[2];

  int t = threadIdx.x, lane = t & 63, wv = t >> 6;
  float bg0 = bg[0];

  if (t < 64) sEp[t] = src[t];
  else if (t < 128) sEp[t] = dst[t-64];
  if (t >= 128 && t < 192) { int j=t-128; sWg[j]=Wg[j]; sBnp[j]=bnp[j]; }
  if (t < 176) ((float4*)&sWnp[0][0])[t] = ((const float4*)Wnp)[t];
  double v[12];
  #pragma unroll
  for (int k=0;k<12;k++) v[k] = (t < NB_BULK) ? partials[t*12+k] : 0.0;
  __syncthreads();
  if (t < 128) {
    int id = sEp[t]; int fo = t;
    for (int i = 0; i < 128; i++) if (sEp[i] == id) { fo = i; break; }
    sMap[t] = fo;
  }
  for (int i = t; i < NSLOT*NFEAT; i += 1024) {
    int s = i / NFEAT, k = i - s*NFEAT;
    sNF[s][k] = nf[(long)sEp[s]*NFEAT + k];
  }
  #pragma unroll
  for (int off=32; off; off>>=1) {
    #pragma unroll
    for (int k=0;k<12;k++) v[k] += __shfl_down(v[k], off);
  }
  if (lane == 0) { for (int k=0;k<12;k++) sA[wv][k] = v[k]; }
  __syncthreads();

  {
    float accE0 = 0.f, accE1 = 0.f, accQ = 0.f, accS0[NFEAT];
    #pragma unroll
    for (int k=0;k<NFEAT;k++) accS0[k] = 0.f;
    #pragma unroll
    for (int it = 0; it < 8; it++) {
      int s = it*16 + wv;
      bool used = (sMap[s] == s);
      float h = states[s*MEM + lane];   // plain load (kernel boundary publishes)
      float h0 = sBnp[lane];
      #pragma unroll
      for (int k=0;k<NFEAT;k++) h0 += sNF[s][k]*sWnp[k][lane];
      float v0 = h0 * sWg[lane];
      float v1 = h * sWg[lane];
      #pragma unroll
      for (int off=32; off; off>>=1) { v0 += __shfl_xor(v0, off); v1 += __shfl_xor(v1, off); }
      float e0 = used ? expf(v0 + bg0) : 0.f;
      float e1 = used ? expf(v1 + bg0) : 0.f;
      accE0 += e0; accE1 += e1;
      #pragma unroll
      for (int k=0;k<NFEAT;k++) accS0[k] += e0*sNF[s][k];
      accQ += e1 * h;
    }
    if (lane == 0) { sE0[wv] = accE0; sE1[wv] = accE1; for (int k=0;k<NFEAT;k++) sS0[wv][k] = accS0[k]; }
    sQ[wv][lane] = accQ;
  }
  __syncthreads();

  if (t < 12) {
    double d = 0.0;
    #pragma unroll
    for (int w=0;w<16;w++) d += sA[w][t];
    sTot[t] = d;
  }
  if (t == 12) { double d=0.0; for (int w=0;w<16;w++) d += (double)sE0[w]; sScal[0] = d; }
  if (t == 13) { double d=0.0; for (int w=0;w<16;w++) d += (double)sE1[w]; sScal[1] = d; }
  __syncthreads();

  if (t < MEM) {
    double Eall = sTot[0] - sScal[0];
    double a = Eall * (double)sBnp[t];
    #pragma unroll
    for (int k=0;k<NFEAT;k++) {
      double S0k = 0.0;
      #pragma unroll
      for (int w=0;w<16;w++) S0k += (double)sS0[w][k];
      a += (sTot[1+k] - S0k) * (double)sWnp[k][t];
    }
    double q = 0.0;
    #pragma unroll
    for (int w=0;w<16;w++) q += (double)sQ[w][t];
    sM[t] = a + q;
  }
  __syncthreads();
  if (t < MEM) {
    double Eall = sTot[0] - sScal[0];
    double den = Eall + sScal[1];
    double a = 0.0;
    #pragma unroll
    for (int m=0;m<MEM;m++) a += sM[m] * (double)Wp[m*MEM + t];
    out[t] = (float)(a/den + (double)bp[t]);
  }
  if (t < NEDGE) done[t] = 0;
}

extern "C" void kernel_launch(void* const* d_in, const int* in_sizes, int n_in,
                              void* d_out, int out_size, void* d_ws, size_t ws_size,
                              hipStream_t stream) {
  (void)in_sizes; (void)n_in; (void)out_size; (void)ws_size;
  const float* nf   = (const float*)d_in[0];
  const int*   src  = (const int*)d_in[1];
  const int*   dst  = (const int*)d_in[2];
  const float* ts   = (const float*)d_in[3];
  const float* ef   = (const float*)d_in[4];
  const float* Wnp  = (const float*)d_in[5];
  const float* bnp  = (const float*)d_in[6];
  const float* Wmsg = (const float*)d_in[7];
  const float* bmsg = (const float*)d_in[8];
  const float* Wih  = (const float*)d_in[9];
  const float* Whh  = (const float*)d_in[10];
  const float* bih  = (const float*)d_in[11];
  const float* bhh  = (const float*)d_in[12];
  const float* w0   = (const float*)d_in[13];
  const float* b0   = (const float*)d_in[14];
  const float* tW   = (const float*)d_in[15];
  const float* tB   = (const float*)d_in[16];
  const float* Wg   = (const float*)d_in[17];
  const float* bg   = (const float*)d_in[18];
  const float* Wp   = (const float*)d_in[19];
  const float* bp   = (const float*)d_in[20];

  double* partials = (double*)((char*)d_ws + WS_PART_OFF);
  float*  states   = (float*)((char*)d_ws + WS_STATES_OFF);
  int*    done     = (int*)((char*)d_ws + WS_DONE_OFF);
  float*  out      = (float*)d_out;

  k_main<<<NEDGE + NB_BULK, 256, 0, stream>>>(
      nf, src, dst, ts, ef, Wnp, bnp, Wmsg, bmsg,
      Wih, Whh, bih, bhh, w0, b0, tW, tB, Wg, bg,
      partials, states, done);
  k_fin<<<1, 1024, 0, stream>>>(nf, src, dst, Wnp, bnp, Wg, bg, Wp, bp,
                                partials, states, done, out);
}